// Round 1
// baseline (1133.511 us; speedup 1.0000x reference)
//
#include <hip/hip_runtime.h>

typedef __bf16 bf16x8 __attribute__((ext_vector_type(8)));
typedef float f32x4 __attribute__((ext_vector_type(4)));
typedef unsigned short u16x8 __attribute__((ext_vector_type(8)));
typedef unsigned short u16x4 __attribute__((ext_vector_type(4)));

#define NSEQ 4096
#define DM 1024
#define LDH 4352
#define NBATCH 4

__device__ __forceinline__ unsigned short f2bf(float f) {
  unsigned u = __float_as_uint(f);
  u += 0x7FFFu + ((u >> 16) & 1u);
  return (unsigned short)(u >> 16);
}
__device__ __forceinline__ float bf2f(unsigned short h) {
  return __uint_as_float(((unsigned)h) << 16);
}
__device__ __forceinline__ float gelu_exact(float x) {
  return 0.5f * x * (1.0f + erff(x * 0.7071067811865475f));
}

// ---------------- LayerNorm: x (f32) -> nx (bf16) ----------------
__global__ __launch_bounds__(256) void ln_kernel(const float* __restrict__ x,
                                                 unsigned short* __restrict__ nx) {
  const int row = blockIdx.x;
  const int tid = threadIdx.x;
  const float4 v = reinterpret_cast<const float4*>(x + (size_t)row * DM)[tid];
  float s = v.x + v.y + v.z + v.w;
  float q = v.x * v.x + v.y * v.y + v.z * v.z + v.w * v.w;
#pragma unroll
  for (int off = 32; off > 0; off >>= 1) {
    s += __shfl_down(s, off);
    q += __shfl_down(q, off);
  }
  __shared__ float ss[4], sq[4];
  if ((tid & 63) == 0) {
    ss[tid >> 6] = s;
    sq[tid >> 6] = q;
  }
  __syncthreads();
  const float ts = ss[0] + ss[1] + ss[2] + ss[3];
  const float tq = sq[0] + sq[1] + sq[2] + sq[3];
  const float mu = ts * (1.0f / DM);
  const float var = tq * (1.0f / DM) - mu * mu;
  const float rs = rsqrtf(var + 1e-5f);
  u16x4 o;
  o[0] = f2bf((v.x - mu) * rs);
  o[1] = f2bf((v.y - mu) * rs);
  o[2] = f2bf((v.z - mu) * rs);
  o[3] = f2bf((v.w - mu) * rs);
  *reinterpret_cast<u16x4*>(nx + (size_t)row * DM + tid * 4) = o;
}

// ---------------- GEMM: C[M,N] = A[M,K](bf16) @ B[K,N](f32->bf16) ----------------
// FINAL=false: store bf16.  FINAL=true: C(f32) = X + A@B.
template <bool FINAL>
__global__ __launch_bounds__(256) void gemm_kernel(
    const unsigned short* __restrict__ A, int lda, const float* __restrict__ B,
    int ldb, void* __restrict__ Cv, int ldc, int K, int ntn,
    const float* __restrict__ X) {
  __shared__ unsigned short As[128][72];
  __shared__ unsigned short Bs[128][72];
  const int tid = threadIdx.x;
  const int bid = blockIdx.x;
  const int m0 = (bid / ntn) * 128;
  const int n0 = (bid % ntn) * 128;
  const int lane = tid & 63;
  const int w = tid >> 6;
  const int lr = lane & 15;
  const int lg = lane >> 4;
  const int wr = (w >> 1) * 64;
  const int wc = (w & 1) * 64;

  f32x4 acc[4][4];
#pragma unroll
  for (int i = 0; i < 4; i++)
#pragma unroll
    for (int j = 0; j < 4; j++)
#pragma unroll
      for (int r = 0; r < 4; r++) acc[i][j][r] = 0.0f;

  for (int k0 = 0; k0 < K; k0 += 64) {
    // stage A: rows of bf16, contiguous 16B per task
#pragma unroll
    for (int t = 0; t < 4; t++) {
      const int task = tid + t * 256;
      const int r = task >> 3, kg = task & 7;
      bf16x8 v = *reinterpret_cast<const bf16x8*>(A + (size_t)(m0 + r) * lda +
                                                  k0 + kg * 8);
      *reinterpret_cast<bf16x8*>(&As[r][kg * 8]) = v;
    }
    // stage B transposed+converted: Bs[c][k] = bf16(B[k0+k][n0+c])
#pragma unroll
    for (int t = 0; t < 4; t++) {
      const int task = tid + t * 256;
      const int c = task & 127, kg = task >> 7;
      const float* bp = B + (size_t)(k0 + kg * 8) * ldb + n0 + c;
      u16x8 uv;
#pragma unroll
      for (int j = 0; j < 8; j++) uv[j] = f2bf(bp[(size_t)j * ldb]);
      *reinterpret_cast<u16x8*>(&Bs[c][kg * 8]) = uv;
    }
    __syncthreads();
#pragma unroll
    for (int kk = 0; kk < 64; kk += 32) {
      bf16x8 af[4], bfr[4];
#pragma unroll
      for (int i = 0; i < 4; i++)
        af[i] =
            *reinterpret_cast<const bf16x8*>(&As[wr + i * 16 + lr][kk + lg * 8]);
#pragma unroll
      for (int j = 0; j < 4; j++)
        bfr[j] =
            *reinterpret_cast<const bf16x8*>(&Bs[wc + j * 16 + lr][kk + lg * 8]);
#pragma unroll
      for (int i = 0; i < 4; i++)
#pragma unroll
        for (int j = 0; j < 4; j++)
          acc[i][j] = __builtin_amdgcn_mfma_f32_16x16x32_bf16(af[i], bfr[j],
                                                              acc[i][j], 0, 0, 0);
    }
    __syncthreads();
  }

  if (FINAL) {
    float* C = reinterpret_cast<float*>(Cv);
#pragma unroll
    for (int i = 0; i < 4; i++)
#pragma unroll
      for (int j = 0; j < 4; j++)
#pragma unroll
        for (int r = 0; r < 4; r++) {
          const int row = m0 + wr + i * 16 + lg * 4 + r;
          const int col = n0 + wc + j * 16 + lr;
          const size_t off = (size_t)row * ldc + col;
          C[off] = X[off] + acc[i][j][r];
        }
  } else {
    unsigned short* C = reinterpret_cast<unsigned short*>(Cv);
#pragma unroll
    for (int i = 0; i < 4; i++)
#pragma unroll
      for (int j = 0; j < 4; j++)
#pragma unroll
        for (int r = 0; r < 4; r++) {
          const int row = m0 + wr + i * 16 + lg * 4 + r;
          const int col = n0 + wc + j * 16 + lr;
          C[(size_t)row * ldc + col] = f2bf(acc[i][j][r]);
        }
  }
}

// ---------------- gate: local = lin * gelu(pg) -> concat[:, 0:1024] ----------------
__global__ __launch_bounds__(256) void gate_local_kernel(
    const unsigned short* __restrict__ h, unsigned short* __restrict__ concat) {
  const int idx = blockIdx.x * 256 + threadIdx.x;
  const int row = idx >> 7;
  const int cg = idx & 127;
  const unsigned short* hr = h + (size_t)row * LDH;
  u16x8 lin = *reinterpret_cast<const u16x8*>(hr + 256 + cg * 8);
  u16x8 pg = *reinterpret_cast<const u16x8*>(hr + 2304 + cg * 8);
  u16x8 o;
#pragma unroll
  for (int j = 0; j < 8; j++) {
    const float l = bf2f(lin[j]);
    const float g = gelu_exact(bf2f(pg[j]));
    o[j] = f2bf(l * g);
  }
  *reinterpret_cast<u16x8*>(concat + (size_t)row * 2048 + cg * 8) = o;
}

// ---------------- gate: v = lin * gelu(pg), stored transposed vT[b][d][n] -------------
__global__ __launch_bounds__(256) void gate_vt_kernel(
    const unsigned short* __restrict__ h, unsigned short* __restrict__ vT) {
  __shared__ unsigned short tbuf[64][72];
  const int n0 = blockIdx.x * 64;
  const int d0 = blockIdx.y * 64;
  const int b = blockIdx.z;
  const int tid = threadIdx.x;
#pragma unroll
  for (int p = 0; p < 2; p++) {
    const int r = p * 32 + (tid >> 3);
    const int cg = tid & 7;
    const unsigned short* hr = h + (size_t)(b * NSEQ + n0 + r) * LDH;
    u16x8 lin = *reinterpret_cast<const u16x8*>(hr + 1280 + d0 + cg * 8);
    u16x8 pg = *reinterpret_cast<const u16x8*>(hr + 3328 + d0 + cg * 8);
    u16x8 o;
#pragma unroll
    for (int j = 0; j < 8; j++) {
      const float l = bf2f(lin[j]);
      const float g = gelu_exact(bf2f(pg[j]));
      o[j] = f2bf(l * g);
    }
    *reinterpret_cast<u16x8*>(&tbuf[r][cg * 8]) = o;
  }
  __syncthreads();
#pragma unroll
  for (int p = 0; p < 2; p++) {
    const int d = p * 32 + (tid >> 3);
    const int ng = tid & 7;
    u16x8 o;
#pragma unroll
    for (int j = 0; j < 8; j++) o[j] = tbuf[ng * 8 + j][d];
    *reinterpret_cast<u16x8*>(vT + (size_t)(b * DM + d0 + d) * NSEQ + n0 +
                              ng * 8) = o;
  }
}

// ---------------- flash attention with sigmoid causal bias ----------------
// Q-tile = 32 rows, KV-tile = 64. 8 waves: phase A each wave one 16x16 S-subtile;
// phase C each wave owns 128 V-cols of the output.
__global__ __launch_bounds__(512) void attn_kernel(
    const unsigned short* __restrict__ h, const unsigned short* __restrict__ vT,
    const float* __restrict__ pbm_ptr, unsigned short* __restrict__ concat) {
  const int qt = blockIdx.x;
  const int b = blockIdx.y;
  const int tid = threadIdx.x;
  const int lane = tid & 63;
  const int w = tid >> 6;
  const int lr = lane & 15;
  const int lg = lane >> 4;
  const float pbm = *pbm_ptr;
  const int n0 = qt * 32;

  const unsigned short* qb = h + (size_t)b * NSEQ * LDH;        // q: cols 0..127
  const unsigned short* kb = qb + 128;                          // k: cols 128..255
  const unsigned short* vtb = vT + (size_t)b * DM * NSEQ;

  __shared__ float S[32][68];
  __shared__ unsigned short P[32][72];
  __shared__ __align__(16) float mArr[32];
  __shared__ __align__(16) float lArr[32];
  __shared__ __align__(16) float cArr[32];

  const int sr = (w >> 2) * 16;
  const int sc = (w & 3) * 16;
  bf16x8 qf[4];
#pragma unroll
  for (int ks = 0; ks < 4; ks++)
    qf[ks] = *reinterpret_cast<const bf16x8*>(
        qb + (size_t)(n0 + sr + lr) * LDH + ks * 32 + lg * 8);

  f32x4 acc[2][8];
#pragma unroll
  for (int rb = 0; rb < 2; rb++)
#pragma unroll
    for (int cbk = 0; cbk < 8; cbk++)
#pragma unroll
      for (int r = 0; r < 4; r++) acc[rb][cbk][r] = 0.0f;
  const int wcol = w * 128;

  if (tid < 32) {
    mArr[tid] = -1e30f;
    lArr[tid] = 0.0f;
  }
  __syncthreads();

  const int kvEnd = n0 + 32;
  for (int kv0 = 0; kv0 < kvEnd; kv0 += 64) {
    // ---- Phase A: S(32x64) = Q . K^T (raw dot; scale+bias applied in B)
    f32x4 sacc;
#pragma unroll
    for (int r = 0; r < 4; r++) sacc[r] = 0.0f;
#pragma unroll
    for (int ks = 0; ks < 4; ks++) {
      bf16x8 kf = *reinterpret_cast<const bf16x8*>(
          kb + (size_t)(kv0 + sc + lr) * LDH + ks * 32 + lg * 8);
      sacc = __builtin_amdgcn_mfma_f32_16x16x32_bf16(qf[ks], kf, sacc, 0, 0, 0);
    }
#pragma unroll
    for (int r = 0; r < 4; r++) S[sr + lg * 4 + r][sc + lr] = sacc[r];
    __syncthreads();

    // ---- Phase B: online softmax (16 threads per row)
    {
      const int row = tid >> 4;
      const int cbase = (tid & 15) * 4;
      const int gn = n0 + row;
      float sv[4];
      float mloc = -1e30f;
#pragma unroll
      for (int e = 0; e < 4; e++) {
        const int gm = kv0 + cbase + e;
        float s;
        if (gm <= gn) {
          const float t = (float)(gm - gn) + pbm;
          const float sig = 1.0f / (1.0f + __expf(-t));
          s = S[row][cbase + e] * 0.08838834764831845f + sig;
        } else {
          s = -1e30f;
        }
        sv[e] = s;
        mloc = fmaxf(mloc, s);
      }
#pragma unroll
      for (int off = 1; off < 16; off <<= 1)
        mloc = fmaxf(mloc, __shfl_xor(mloc, off));
      const float mprev = mArr[row];
      const float mnew = fmaxf(mprev, mloc);
      const float c = __expf(mprev - mnew);
      float psum = 0.0f;
      u16x4 pv;
#pragma unroll
      for (int e = 0; e < 4; e++) {
        const float p = __expf(sv[e] - mnew);
        psum += p;
        pv[e] = f2bf(p);
      }
      *reinterpret_cast<u16x4*>(&P[row][cbase]) = pv;
#pragma unroll
      for (int off = 1; off < 16; off <<= 1) psum += __shfl_xor(psum, off);
      if ((tid & 15) == 0) {
        mArr[row] = mnew;
        cArr[row] = c;
        lArr[row] = lArr[row] * c + psum;
      }
    }
    __syncthreads();

    // ---- Phase C: rescale acc, then acc += P . V  (this wave's 128 cols)
#pragma unroll
    for (int rb = 0; rb < 2; rb++) {
      f32x4 cv = *reinterpret_cast<const f32x4*>(&cArr[rb * 16 + lg * 4]);
#pragma unroll
      for (int cbk = 0; cbk < 8; cbk++)
#pragma unroll
        for (int r = 0; r < 4; r++) acc[rb][cbk][r] *= cv[r];
    }
#pragma unroll
    for (int kk = 0; kk < 2; kk++) {
      bf16x8 ap[2];
#pragma unroll
      for (int rb = 0; rb < 2; rb++)
        ap[rb] = *reinterpret_cast<const bf16x8*>(
            &P[rb * 16 + lr][kk * 32 + lg * 8]);
#pragma unroll
      for (int cbk = 0; cbk < 8; cbk++) {
        bf16x8 bv = *reinterpret_cast<const bf16x8*>(
            vtb + (size_t)(wcol + cbk * 16 + lr) * NSEQ + kv0 + kk * 32 +
            lg * 8);
#pragma unroll
        for (int rb = 0; rb < 2; rb++)
          acc[rb][cbk] = __builtin_amdgcn_mfma_f32_16x16x32_bf16(
              ap[rb], bv, acc[rb][cbk], 0, 0, 0);
      }
    }
    __syncthreads();
  }

  // ---- epilogue: normalize by l and write attn into concat[:, 1024:2048]
#pragma unroll
  for (int rb = 0; rb < 2; rb++) {
    f32x4 lv = *reinterpret_cast<const f32x4*>(&lArr[rb * 16 + lg * 4]);
    f32x4 inv;
#pragma unroll
    for (int r = 0; r < 4; r++) inv[r] = 1.0f / lv[r];
#pragma unroll
    for (int cbk = 0; cbk < 8; cbk++)
#pragma unroll
      for (int r = 0; r < 4; r++) {
        const int grow = b * NSEQ + n0 + rb * 16 + lg * 4 + r;
        const int col = 1024 + wcol + cbk * 16 + lr;
        concat[(size_t)grow * 2048 + col] = f2bf(acc[rb][cbk][r] * inv[r]);
      }
  }
}

extern "C" void kernel_launch(void* const* d_in, const int* in_sizes, int n_in,
                              void* d_out, int out_size, void* d_ws,
                              size_t ws_size, hipStream_t stream) {
  (void)in_sizes;
  (void)n_in;
  (void)out_size;
  const float* x = (const float*)d_in[0];
  const float* expand = (const float*)d_in[1];
  const float* project = (const float*)d_in[2];
  const float* pbm = (const float*)d_in[3];
  float* out = (float*)d_out;

  const size_t H_BYTES = (size_t)16384 * LDH * 2;     // 142,606,336
  const size_t CAT_BYTES = (size_t)16384 * 2048 * 2;  // 67,108,864
  const size_t NX_BYTES = (size_t)16384 * DM * 2;     // 33,554,432 (aliased w/ vT)
  if (ws_size < H_BYTES + CAT_BYTES + NX_BYTES) return;

  char* ws = (char*)d_ws;
  unsigned short* h = (unsigned short*)ws;
  unsigned short* concat = (unsigned short*)(ws + H_BYTES);
  unsigned short* nx = (unsigned short*)(ws + H_BYTES + CAT_BYTES);
  unsigned short* vT = nx;  // nx dead after GEMM1; same size

  // 1. LayerNorm
  ln_kernel<<<16384, 256, 0, stream>>>(x, nx);
  // 2. h = nx @ expand  (M=16384, N=4352, K=1024)
  gemm_kernel<false><<<dim3(128 * 34), 256, 0, stream>>>(
      nx, DM, expand, LDH, (void*)h, LDH, DM, 34, nullptr);
  // 3. local half of concat
  gate_local_kernel<<<8192, 256, 0, stream>>>(h, concat);
  // 4. v, transposed
  gate_vt_kernel<<<dim3(64, 16, 4), 256, 0, stream>>>(h, vT);
  // 5. attention -> concat[:, 1024:2048]
  attn_kernel<<<dim3(128, 4), 512, 0, stream>>>(h, vT, pbm, concat);
  // 6. out = x + concat @ project  (M=16384, N=1024, K=2048)
  gemm_kernel<true><<<dim3(128 * 8), 256, 0, stream>>>(
      concat, 2048, project, DM, (void*)out, DM, 2048, 8, x);
}

// Round 4
// 708.688 us; speedup vs baseline: 1.5994x; 1.5994x over previous
//
#include <hip/hip_runtime.h>
#include <type_traits>

typedef __bf16 bf16x8 __attribute__((ext_vector_type(8)));
typedef __bf16 bf16x4v __attribute__((ext_vector_type(4)));
typedef float f32x4 __attribute__((ext_vector_type(4)));
typedef unsigned short u16x8 __attribute__((ext_vector_type(8)));
typedef unsigned short u16x4 __attribute__((ext_vector_type(4)));

#define NSEQ 4096
#define DM 1024
#define LDH 4352
#define NBATCH 4

__device__ __forceinline__ unsigned short f2bf(float f) {
  unsigned u = __float_as_uint(f);
  u += 0x7FFFu + ((u >> 16) & 1u);
  return (unsigned short)(u >> 16);
}
__device__ __forceinline__ float bf2f(unsigned short h) {
  return __uint_as_float(((unsigned)h) << 16);
}
__device__ __forceinline__ float gelu_exact(float x) {
  return 0.5f * x * (1.0f + erff(x * 0.7071067811865475f));
}

// ---------------- LayerNorm: x (f32) -> nx (bf16) ----------------
__global__ __launch_bounds__(256) void ln_kernel(const float* __restrict__ x,
                                                 unsigned short* __restrict__ nx) {
  const int row = blockIdx.x;
  const int tid = threadIdx.x;
  const float4 v = reinterpret_cast<const float4*>(x + (size_t)row * DM)[tid];
  float s = v.x + v.y + v.z + v.w;
  float q = v.x * v.x + v.y * v.y + v.z * v.z + v.w * v.w;
#pragma unroll
  for (int off = 32; off > 0; off >>= 1) {
    s += __shfl_down(s, off);
    q += __shfl_down(q, off);
  }
  __shared__ float ss[4], sq[4];
  if ((tid & 63) == 0) {
    ss[tid >> 6] = s;
    sq[tid >> 6] = q;
  }
  __syncthreads();
  const float ts = ss[0] + ss[1] + ss[2] + ss[3];
  const float tq = sq[0] + sq[1] + sq[2] + sq[3];
  const float mu = ts * (1.0f / DM);
  const float var = tq * (1.0f / DM) - mu * mu;
  const float rs = rsqrtf(var + 1e-5f);
  u16x4 o;
  o[0] = f2bf((v.x - mu) * rs);
  o[1] = f2bf((v.y - mu) * rs);
  o[2] = f2bf((v.z - mu) * rs);
  o[3] = f2bf((v.w - mu) * rs);
  *reinterpret_cast<u16x4*>(nx + (size_t)row * DM + tid * 4) = o;
}

// ---------------- GEMM: C[M,N] = A[M,K](bf16) @ B[K,N](f32->bf16) ----------------
template <bool FINAL>
__global__ __launch_bounds__(256) void gemm_kernel(
    const unsigned short* __restrict__ A, int lda, const float* __restrict__ B,
    int ldb, void* __restrict__ Cv, int ldc, int K, int ntn,
    const float* __restrict__ X) {
  __shared__ unsigned short As[128][72];
  __shared__ unsigned short Bs[128][72];
  const int tid = threadIdx.x;
  const int bid = blockIdx.x;
  const int m0 = (bid / ntn) * 128;
  const int n0 = (bid % ntn) * 128;
  const int lane = tid & 63;
  const int w = tid >> 6;
  const int lr = lane & 15;
  const int lg = lane >> 4;
  const int wr = (w >> 1) * 64;
  const int wc = (w & 1) * 64;

  f32x4 acc[4][4];
#pragma unroll
  for (int i = 0; i < 4; i++)
#pragma unroll
    for (int j = 0; j < 4; j++)
#pragma unroll
      for (int r = 0; r < 4; r++) acc[i][j][r] = 0.0f;

  for (int k0 = 0; k0 < K; k0 += 64) {
#pragma unroll
    for (int t = 0; t < 4; t++) {
      const int task = tid + t * 256;
      const int r = task >> 3, kg = task & 7;
      bf16x8 v = *reinterpret_cast<const bf16x8*>(A + (size_t)(m0 + r) * lda +
                                                  k0 + kg * 8);
      *reinterpret_cast<bf16x8*>(&As[r][kg * 8]) = v;
    }
#pragma unroll
    for (int t = 0; t < 4; t++) {
      const int task = tid + t * 256;
      const int c = task & 127, kg = task >> 7;
      const float* bp = B + (size_t)(k0 + kg * 8) * ldb + n0 + c;
      u16x8 uv;
#pragma unroll
      for (int j = 0; j < 8; j++) uv[j] = f2bf(bp[(size_t)j * ldb]);
      *reinterpret_cast<u16x8*>(&Bs[c][kg * 8]) = uv;
    }
    __syncthreads();
#pragma unroll
    for (int kk = 0; kk < 64; kk += 32) {
      bf16x8 af[4], bfr[4];
#pragma unroll
      for (int i = 0; i < 4; i++)
        af[i] =
            *reinterpret_cast<const bf16x8*>(&As[wr + i * 16 + lr][kk + lg * 8]);
#pragma unroll
      for (int j = 0; j < 4; j++)
        bfr[j] =
            *reinterpret_cast<const bf16x8*>(&Bs[wc + j * 16 + lr][kk + lg * 8]);
#pragma unroll
      for (int i = 0; i < 4; i++)
#pragma unroll
        for (int j = 0; j < 4; j++)
          acc[i][j] = __builtin_amdgcn_mfma_f32_16x16x32_bf16(af[i], bfr[j],
                                                              acc[i][j], 0, 0, 0);
    }
    __syncthreads();
  }

  if (FINAL) {
    float* C = reinterpret_cast<float*>(Cv);
#pragma unroll
    for (int i = 0; i < 4; i++)
#pragma unroll
      for (int j = 0; j < 4; j++)
#pragma unroll
        for (int r = 0; r < 4; r++) {
          const int row = m0 + wr + i * 16 + lg * 4 + r;
          const int col = n0 + wc + j * 16 + lr;
          const size_t off = (size_t)row * ldc + col;
          C[off] = X[off] + acc[i][j][r];
        }
  } else {
    unsigned short* C = reinterpret_cast<unsigned short*>(Cv);
#pragma unroll
    for (int i = 0; i < 4; i++)
#pragma unroll
      for (int j = 0; j < 4; j++)
#pragma unroll
        for (int r = 0; r < 4; r++) {
          const int row = m0 + wr + i * 16 + lg * 4 + r;
          const int col = n0 + wc + j * 16 + lr;
          C[(size_t)row * ldc + col] = f2bf(acc[i][j][r]);
        }
  }
}

// ---------------- gate: local = lin * gelu(pg) -> concat[:, 0:1024] ----------------
__global__ __launch_bounds__(256) void gate_local_kernel(
    const unsigned short* __restrict__ h, unsigned short* __restrict__ concat) {
  const int idx = blockIdx.x * 256 + threadIdx.x;
  const int row = idx >> 7;
  const int cg = idx & 127;
  const unsigned short* hr = h + (size_t)row * LDH;
  u16x8 lin = *reinterpret_cast<const u16x8*>(hr + 256 + cg * 8);
  u16x8 pg = *reinterpret_cast<const u16x8*>(hr + 2304 + cg * 8);
  u16x8 o;
#pragma unroll
  for (int j = 0; j < 8; j++) {
    const float l = bf2f(lin[j]);
    const float g = gelu_exact(bf2f(pg[j]));
    o[j] = f2bf(l * g);
  }
  *reinterpret_cast<u16x8*>(concat + (size_t)row * 2048 + cg * 8) = o;
}

// ---------------- gate: v = lin * gelu(pg), stored transposed vT[b][d][n] -------------
__global__ __launch_bounds__(256) void gate_vt_kernel(
    const unsigned short* __restrict__ h, unsigned short* __restrict__ vT) {
  __shared__ unsigned short tbuf[64][72];
  const int n0 = blockIdx.x * 64;
  const int d0 = blockIdx.y * 64;
  const int b = blockIdx.z;
  const int tid = threadIdx.x;
#pragma unroll
  for (int p = 0; p < 2; p++) {
    const int r = p * 32 + (tid >> 3);
    const int cg = tid & 7;
    const unsigned short* hr = h + (size_t)(b * NSEQ + n0 + r) * LDH;
    u16x8 lin = *reinterpret_cast<const u16x8*>(hr + 1280 + d0 + cg * 8);
    u16x8 pg = *reinterpret_cast<const u16x8*>(hr + 3328 + d0 + cg * 8);
    u16x8 o;
#pragma unroll
    for (int j = 0; j < 8; j++) {
      const float l = bf2f(lin[j]);
      const float g = gelu_exact(bf2f(pg[j]));
      o[j] = f2bf(l * g);
    }
    *reinterpret_cast<u16x8*>(&tbuf[r][cg * 8]) = o;
  }
  __syncthreads();
#pragma unroll
  for (int p = 0; p < 2; p++) {
    const int d = p * 32 + (tid >> 3);
    const int ng = tid & 7;
    u16x8 o;
#pragma unroll
    for (int j = 0; j < 8; j++) o[j] = tbuf[ng * 8 + j][d];
    *reinterpret_cast<u16x8*>(vT + (size_t)(b * DM + d0 + d) * NSEQ + n0 +
                              ng * 8) = o;
  }
}

// ---------------- flash attention, balanced tile pairs ----------------
// Block = 512 thr (8 waves). Per block: two q-tiles {qt, 31-qt} of 128 rows,
// d-slice of 128 (dc in [0,8)). Wave w owns q-rows [16w,16w+16) for S/softmax
// (swapped mfma(K,Q): row stats fully in-register). PV: wave (wr,wc) computes
// q[wr*64 +: 64] x d[wc*32 +: 32]. 2 barriers per KV-iter. K double-buffered
// in LDS; defer-max (THR=8) keeps the acc rescale rare.
// Round-3 bug fixed here: Ks inner dim must hold 128 bf16 cols (+8 pad) —
// [2][64][72] aliased buffers & clobbered cArr (race via stage prefetch).
__global__ __launch_bounds__(512, 4) void attn_kernel(
    const unsigned short* __restrict__ h, const unsigned short* __restrict__ vT,
    const float* __restrict__ pbm_ptr, unsigned short* __restrict__ concat) {
  __shared__ __align__(16) unsigned short P[128][72];
  __shared__ __align__(16) unsigned short Ks[2][64][136];
  __shared__ __align__(16) float cArr[128];
  __shared__ __align__(16) float lArr[128];

  const int tid = threadIdx.x;
  const int lane = tid & 63;
  const int w = tid >> 6;   // 0..7
  const int lq = lane & 15;
  const int lg = lane >> 4;
  const int wr = w >> 2;    // 0..1
  const int wc = w & 3;     // 0..3
  const int bid = blockIdx.x;
  const int pair = bid >> 5;       // 0..15
  const int dcb = bid & 31;
  const int dc = dcb & 7;          // 0..7
  const int b = dcb >> 3;          // 0..3
  const float pbm = *pbm_ptr;
  const float SCALE = 0.08838834764831845f;

  const unsigned short* qb = h + (size_t)b * NSEQ * LDH;  // q cols 0..127
  const unsigned short* kb = qb + 128;                    // k cols 128..255
  const unsigned short* vtb = vT + (size_t)b * DM * NSEQ;

  auto stage = [&](int bufI, int kv0s) {
#pragma unroll
    for (int p = 0; p < 2; p++) {
      const int task = tid + p * 512;
      const int row = task >> 4;
      const int ch = task & 15;
      bf16x8 v = *reinterpret_cast<const bf16x8*>(
          kb + (size_t)(kv0s + row) * LDH + ch * 8);
      *reinterpret_cast<bf16x8*>(&Ks[bufI][row][ch * 8]) = v;
    }
  };

#pragma unroll 1
  for (int t = 0; t < 2; t++) {
    const int qt = (t == 0) ? pair : (31 - pair);
    const int N0 = qt * 128;
    const int qrow = N0 + w * 16 + lq;

    bf16x8 qf[4];
#pragma unroll
    for (int ks = 0; ks < 4; ks++)
      qf[ks] = *reinterpret_cast<const bf16x8*>(
          qb + (size_t)qrow * LDH + ks * 32 + lg * 8);

    f32x4 acc[4][2];
#pragma unroll
    for (int i = 0; i < 4; i++)
#pragma unroll
      for (int j = 0; j < 2; j++)
#pragma unroll
        for (int r = 0; r < 4; r++) acc[i][j][r] = 0.0f;
    float m = -1e30f, lsum = 0.0f;
    int buf = 0;

    stage(0, 0);
    __syncthreads();

    auto body = [&](int kv0, auto BIASC, auto MASKC) {
      constexpr bool BIAS = decltype(BIASC)::value;
      constexpr bool MASK = decltype(MASKC)::value;
      // ---- S phase: sa[sub] = K(16kv x 128) . Q(own 16 q) -- swapped mfma
      f32x4 sa[4];
#pragma unroll
      for (int sub = 0; sub < 4; sub++)
#pragma unroll
        for (int r = 0; r < 4; r++) sa[sub][r] = 0.0f;
#pragma unroll
      for (int ks = 0; ks < 4; ks++)
#pragma unroll
        for (int sub = 0; sub < 4; sub++) {
          bf16x8 kf = *reinterpret_cast<const bf16x8*>(
              &Ks[buf][sub * 16 + lq][ks * 32 + lg * 8]);
          sa[sub] =
              __builtin_amdgcn_mfma_f32_16x16x32_bf16(kf, qf[ks], sa[sub], 0, 0, 0);
        }
      // lane holds S[kv = kv0+sub*16+lg*4+r][q = qrow]
      float mloc = -1e30f;
#pragma unroll
      for (int sub = 0; sub < 4; sub++)
#pragma unroll
        for (int r = 0; r < 4; r++) {
          float s = sa[sub][r] * SCALE;
          if (BIAS) {
            const int kv = kv0 + sub * 16 + lg * 4 + r;
            if (MASK && kv > qrow) {
              s = -1e30f;
            } else {
              const float dn = (float)(kv - qrow) + pbm;
              s += 1.0f / (1.0f + __expf(-dn));
            }
          }
          sa[sub][r] = s;
          mloc = fmaxf(mloc, s);
        }
      mloc = fmaxf(mloc, __shfl_xor(mloc, 16));
      mloc = fmaxf(mloc, __shfl_xor(mloc, 32));
      float c = 1.0f;
      if (mloc > m + 8.0f) {  // defer-max: rescale only on large growth
        c = __expf(m - mloc);
        m = mloc;
      }
      float ps = 0.0f;
#pragma unroll
      for (int sub = 0; sub < 4; sub++) {
        bf16x4v pv;
#pragma unroll
        for (int r = 0; r < 4; r++) {
          const float p = __expf(sa[sub][r] - m);
          ps += p;
          pv[r] = (__bf16)p;
        }
        *reinterpret_cast<bf16x4v*>(&P[w * 16 + lq][sub * 16 + lg * 4]) = pv;
      }
      ps += __shfl_xor(ps, 16);
      ps += __shfl_xor(ps, 32);
      lsum = lsum * c + ps;
      if (lane < 16) cArr[w * 16 + lane] = c;
      if (kv0 < N0 + 64) stage(buf ^ 1, kv0 + 64);
      __syncthreads();

      // ---- PV phase
      bool need = false;
      f32x4 cv[4];
#pragma unroll
      for (int i = 0; i < 4; i++) {
        cv[i] = *reinterpret_cast<const f32x4*>(&cArr[wr * 64 + i * 16 + lg * 4]);
#pragma unroll
        for (int r = 0; r < 4; r++) need |= (cv[i][r] != 1.0f);
      }
      if (__any(need)) {
#pragma unroll
        for (int i = 0; i < 4; i++)
#pragma unroll
          for (int j = 0; j < 2; j++)
#pragma unroll
            for (int r = 0; r < 4; r++) acc[i][j][r] *= cv[i][r];
      }
      __builtin_amdgcn_s_setprio(1);
#pragma unroll
      for (int ks = 0; ks < 2; ks++) {
        bf16x8 pa[4];
#pragma unroll
        for (int i = 0; i < 4; i++)
          pa[i] = *reinterpret_cast<const bf16x8*>(
              &P[wr * 64 + i * 16 + lq][ks * 32 + lg * 8]);
#pragma unroll
        for (int j = 0; j < 2; j++) {
          bf16x8 bv = *reinterpret_cast<const bf16x8*>(
              vtb + (size_t)(dc * 128 + wc * 32 + j * 16 + lq) * NSEQ + kv0 +
              ks * 32 + lg * 8);
#pragma unroll
          for (int i = 0; i < 4; i++)
            acc[i][j] = __builtin_amdgcn_mfma_f32_16x16x32_bf16(pa[i], bv,
                                                                acc[i][j], 0, 0, 0);
        }
      }
      __builtin_amdgcn_s_setprio(0);
      __syncthreads();
      buf ^= 1;
    };

    for (int kv0 = 0; kv0 + 128 <= N0; kv0 += 64)
      body(kv0, std::false_type{}, std::false_type{});
    if (N0 >= 64) body(N0 - 64, std::true_type{}, std::false_type{});
    body(N0, std::true_type{}, std::true_type{});
    body(N0 + 64, std::true_type{}, std::true_type{});

    // ---- epilogue: normalize, write attn half of concat
    if (lane < 16) lArr[w * 16 + lane] = lsum;
    __syncthreads();
#pragma unroll
    for (int i = 0; i < 4; i++) {
      f32x4 lv = *reinterpret_cast<const f32x4*>(&lArr[wr * 64 + i * 16 + lg * 4]);
      f32x4 inv;
#pragma unroll
      for (int r = 0; r < 4; r++) inv[r] = 1.0f / lv[r];
#pragma unroll
      for (int j = 0; j < 2; j++)
#pragma unroll
        for (int r = 0; r < 4; r++) {
          const int grow = b * NSEQ + N0 + wr * 64 + i * 16 + lg * 4 + r;
          const int col = 1024 + dc * 128 + wc * 32 + j * 16 + lq;
          concat[(size_t)grow * 2048 + col] = f2bf(acc[i][j][r] * inv[r]);
        }
    }
    if (t == 0) __syncthreads();
  }
}

extern "C" void kernel_launch(void* const* d_in, const int* in_sizes, int n_in,
                              void* d_out, int out_size, void* d_ws,
                              size_t ws_size, hipStream_t stream) {
  (void)in_sizes;
  (void)n_in;
  (void)out_size;
  const float* x = (const float*)d_in[0];
  const float* expand = (const float*)d_in[1];
  const float* project = (const float*)d_in[2];
  const float* pbm = (const float*)d_in[3];
  float* out = (float*)d_out;

  const size_t H_BYTES = (size_t)16384 * LDH * 2;
  const size_t CAT_BYTES = (size_t)16384 * 2048 * 2;
  const size_t NX_BYTES = (size_t)16384 * DM * 2;
  if (ws_size < H_BYTES + CAT_BYTES + NX_BYTES) return;

  char* ws = (char*)d_ws;
  unsigned short* h = (unsigned short*)ws;
  unsigned short* concat = (unsigned short*)(ws + H_BYTES);
  unsigned short* nx = (unsigned short*)(ws + H_BYTES + CAT_BYTES);
  unsigned short* vT = nx;  // nx dead after GEMM1; same size

  ln_kernel<<<16384, 256, 0, stream>>>(x, nx);
  gemm_kernel<false><<<dim3(128 * 34), 256, 0, stream>>>(
      nx, DM, expand, LDH, (void*)h, LDH, DM, 34, nullptr);
  gate_local_kernel<<<8192, 256, 0, stream>>>(h, concat);
  gate_vt_kernel<<<dim3(64, 16, 4), 256, 0, stream>>>(h, vT);
  attn_kernel<<<dim3(512), 512, 0, stream>>>(h, vT, pbm, concat);
  gemm_kernel<true><<<dim3(128 * 8), 256, 0, stream>>>(
      concat, 2048, project, DM, (void*)out, DM, 2048, 8, x);
}

// Round 5
// 600.777 us; speedup vs baseline: 1.8867x; 1.1796x over previous
//
#include <hip/hip_runtime.h>
#include <type_traits>

typedef __bf16 bf16x8 __attribute__((ext_vector_type(8)));
typedef __bf16 bf16x4v __attribute__((ext_vector_type(4)));
typedef float f32x4 __attribute__((ext_vector_type(4)));
typedef unsigned short u16x8 __attribute__((ext_vector_type(8)));
typedef unsigned short u16x4 __attribute__((ext_vector_type(4)));

#define NSEQ 4096
#define DM 1024
#define LDH 4352
#define NBATCH 4

__device__ __forceinline__ unsigned short f2bf(float f) {
  unsigned u = __float_as_uint(f);
  u += 0x7FFFu + ((u >> 16) & 1u);
  return (unsigned short)(u >> 16);
}
__device__ __forceinline__ float bf2f(unsigned short h) {
  return __uint_as_float(((unsigned)h) << 16);
}
__device__ __forceinline__ float gelu_exact(float x) {
  return 0.5f * x * (1.0f + erff(x * 0.7071067811865475f));
}

// async global->LDS, 16B per lane; lds dst is wave-uniform base + lane*16
__device__ __forceinline__ void gload_lds16(const unsigned short* src,
                                            unsigned short* dst) {
  __builtin_amdgcn_global_load_lds(
      (const __attribute__((address_space(1))) unsigned int*)src,
      (__attribute__((address_space(3))) unsigned int*)dst, 16, 0, 0);
}

// ---------------- LayerNorm: x (f32) -> nx (bf16) ----------------
__global__ __launch_bounds__(256) void ln_kernel(const float* __restrict__ x,
                                                 unsigned short* __restrict__ nx) {
  const int row = blockIdx.x;
  const int tid = threadIdx.x;
  const float4 v = reinterpret_cast<const float4*>(x + (size_t)row * DM)[tid];
  float s = v.x + v.y + v.z + v.w;
  float q = v.x * v.x + v.y * v.y + v.z * v.z + v.w * v.w;
#pragma unroll
  for (int off = 32; off > 0; off >>= 1) {
    s += __shfl_down(s, off);
    q += __shfl_down(q, off);
  }
  __shared__ float ss[4], sq[4];
  if ((tid & 63) == 0) {
    ss[tid >> 6] = s;
    sq[tid >> 6] = q;
  }
  __syncthreads();
  const float ts = ss[0] + ss[1] + ss[2] + ss[3];
  const float tq = sq[0] + sq[1] + sq[2] + sq[3];
  const float mu = ts * (1.0f / DM);
  const float var = tq * (1.0f / DM) - mu * mu;
  const float rs = rsqrtf(var + 1e-5f);
  u16x4 o;
  o[0] = f2bf((v.x - mu) * rs);
  o[1] = f2bf((v.y - mu) * rs);
  o[2] = f2bf((v.z - mu) * rs);
  o[3] = f2bf((v.w - mu) * rs);
  *reinterpret_cast<u16x4*>(nx + (size_t)row * DM + tid * 4) = o;
}

// ---------------- transpose+convert: in f32 [K][N] -> out bf16 [N][K] -------------
__global__ __launch_bounds__(256) void tconv_kernel(const float* __restrict__ in,
                                                    unsigned short* __restrict__ out,
                                                    int K, int N) {
  __shared__ unsigned short tile[64][72];
  const int n0 = blockIdx.x * 64;
  const int k0 = blockIdx.y * 64;
  const int tid = threadIdx.x;
  const int lr = tid >> 4, lc = (tid & 15) * 4;
#pragma unroll
  for (int p = 0; p < 4; p++) {
    const int r = lr + p * 16;
    float4 v = *reinterpret_cast<const float4*>(in + (size_t)(k0 + r) * N + n0 + lc);
    tile[r][lc + 0] = f2bf(v.x);
    tile[r][lc + 1] = f2bf(v.y);
    tile[r][lc + 2] = f2bf(v.z);
    tile[r][lc + 3] = f2bf(v.w);
  }
  __syncthreads();
  const int nn = tid >> 2, kkg = (tid & 3) * 16;
  u16x8 o0, o1;
#pragma unroll
  for (int j = 0; j < 8; j++) {
    o0[j] = tile[kkg + j][nn];
    o1[j] = tile[kkg + 8 + j][nn];
  }
  unsigned short* dst = out + (size_t)(n0 + nn) * K + k0 + kkg;
  *reinterpret_cast<u16x8*>(dst) = o0;
  *reinterpret_cast<u16x8*>(dst + 8) = o1;
}

// ---------------- GEMM (m97 structure): C[M,N] = A[M,K] @ Bt[N,K] (both bf16) ------
// A row-major [M][lda], Bt row-major [N][ldb]; staging via global_load_lds x16B.
// FINAL=false: store bf16 to C[ldc].  FINAL=true: C(f32) = X + A@Bt^T.
template <bool FINAL>
__global__ __launch_bounds__(256, 4) void gemm_kernel(
    const unsigned short* __restrict__ A, int lda,
    const unsigned short* __restrict__ Bt, int ldb, void* __restrict__ Cv,
    int ldc, int K, int ntn, const float* __restrict__ X) {
  __shared__ unsigned short As[128][64];
  __shared__ unsigned short Bs[128][64];
  const int tid = threadIdx.x;
  const int bid = blockIdx.x;
  const int m0 = (bid / ntn) * 128;
  const int n0 = (bid % ntn) * 128;
  const int lane = tid & 63;
  const int w = tid >> 6;
  const int lr = lane & 15;
  const int lg = lane >> 4;
  const int wr = (w >> 1) * 64;
  const int wc = (w & 1) * 64;

  f32x4 acc[4][4];
#pragma unroll
  for (int i = 0; i < 4; i++)
#pragma unroll
    for (int j = 0; j < 4; j++)
#pragma unroll
      for (int r = 0; r < 4; r++) acc[i][j][r] = 0.0f;

  for (int k0 = 0; k0 < K; k0 += 64) {
    // stage A and B tiles: [128][64] bf16 linear, wave w owns bytes [w*4K,(w+1)*4K)
#pragma unroll
    for (int j = 0; j < 4; j++) {
      const int boff = w * 4096 + j * 1024 + lane * 16;  // byte offset in tile
      const int row = boff >> 7;                         // /128 bytes per row
      const int col = (boff & 127) >> 1;                 // bf16 col
      gload_lds16(A + (size_t)(m0 + row) * lda + k0 + col,
                  &As[0][0] + (boff - lane * 16) / 2);
    }
#pragma unroll
    for (int j = 0; j < 4; j++) {
      const int boff = w * 4096 + j * 1024 + lane * 16;
      const int row = boff >> 7;
      const int col = (boff & 127) >> 1;
      gload_lds16(Bt + (size_t)(n0 + row) * ldb + k0 + col,
                  &Bs[0][0] + (boff - lane * 16) / 2);
    }
    __syncthreads();
#pragma unroll
    for (int kk = 0; kk < 64; kk += 32) {
      bf16x8 af[4], bfr[4];
#pragma unroll
      for (int i = 0; i < 4; i++)
        af[i] =
            *reinterpret_cast<const bf16x8*>(&As[wr + i * 16 + lr][kk + lg * 8]);
#pragma unroll
      for (int j = 0; j < 4; j++)
        bfr[j] =
            *reinterpret_cast<const bf16x8*>(&Bs[wc + j * 16 + lr][kk + lg * 8]);
#pragma unroll
      for (int i = 0; i < 4; i++)
#pragma unroll
        for (int j = 0; j < 4; j++)
          acc[i][j] = __builtin_amdgcn_mfma_f32_16x16x32_bf16(af[i], bfr[j],
                                                              acc[i][j], 0, 0, 0);
    }
    __syncthreads();
  }

  if (FINAL) {
    float* C = reinterpret_cast<float*>(Cv);
#pragma unroll
    for (int i = 0; i < 4; i++)
#pragma unroll
      for (int j = 0; j < 4; j++)
#pragma unroll
        for (int r = 0; r < 4; r++) {
          const int row = m0 + wr + i * 16 + lg * 4 + r;
          const int col = n0 + wc + j * 16 + lr;
          const size_t off = (size_t)row * ldc + col;
          C[off] = X[off] + acc[i][j][r];
        }
  } else {
    unsigned short* C = reinterpret_cast<unsigned short*>(Cv);
#pragma unroll
    for (int i = 0; i < 4; i++)
#pragma unroll
      for (int j = 0; j < 4; j++)
#pragma unroll
        for (int r = 0; r < 4; r++) {
          const int row = m0 + wr + i * 16 + lg * 4 + r;
          const int col = n0 + wc + j * 16 + lr;
          C[(size_t)row * ldc + col] = f2bf(acc[i][j][r]);
        }
  }
}

// ---------------- gate: local = lin * gelu(pg) -> concat[:, 0:1024] ----------------
__global__ __launch_bounds__(256) void gate_local_kernel(
    const unsigned short* __restrict__ h, unsigned short* __restrict__ concat) {
  const int idx = blockIdx.x * 256 + threadIdx.x;
  const int row = idx >> 7;
  const int cg = idx & 127;
  const unsigned short* hr = h + (size_t)row * LDH;
  u16x8 lin = *reinterpret_cast<const u16x8*>(hr + 256 + cg * 8);
  u16x8 pg = *reinterpret_cast<const u16x8*>(hr + 2304 + cg * 8);
  u16x8 o;
#pragma unroll
  for (int j = 0; j < 8; j++) {
    const float l = bf2f(lin[j]);
    const float g = gelu_exact(bf2f(pg[j]));
    o[j] = f2bf(l * g);
  }
  *reinterpret_cast<u16x8*>(concat + (size_t)row * 2048 + cg * 8) = o;
}

// ---------------- gate: v = lin * gelu(pg), stored transposed vT[b][d][n] -------------
__global__ __launch_bounds__(256) void gate_vt_kernel(
    const unsigned short* __restrict__ h, unsigned short* __restrict__ vT) {
  __shared__ unsigned short tbuf[64][72];
  const int n0 = blockIdx.x * 64;
  const int d0 = blockIdx.y * 64;
  const int b = blockIdx.z;
  const int tid = threadIdx.x;
#pragma unroll
  for (int p = 0; p < 2; p++) {
    const int r = p * 32 + (tid >> 3);
    const int cg = tid & 7;
    const unsigned short* hr = h + (size_t)(b * NSEQ + n0 + r) * LDH;
    u16x8 lin = *reinterpret_cast<const u16x8*>(hr + 1280 + d0 + cg * 8);
    u16x8 pg = *reinterpret_cast<const u16x8*>(hr + 3328 + d0 + cg * 8);
    u16x8 o;
#pragma unroll
    for (int j = 0; j < 8; j++) {
      const float l = bf2f(lin[j]);
      const float g = gelu_exact(bf2f(pg[j]));
      o[j] = f2bf(l * g);
    }
    *reinterpret_cast<u16x8*>(&tbuf[r][cg * 8]) = o;
  }
  __syncthreads();
#pragma unroll
  for (int p = 0; p < 2; p++) {
    const int d = p * 32 + (tid >> 3);
    const int ng = tid & 7;
    u16x8 o;
#pragma unroll
    for (int j = 0; j < 8; j++) o[j] = tbuf[ng * 8 + j][d];
    *reinterpret_cast<u16x8*>(vT + (size_t)(b * DM + d0 + d) * NSEQ + n0 +
                              ng * 8) = o;
  }
}

// ---------------- flash attention, balanced tile pairs ----------------
// (unchanged structure; P stride 72->80 u16 so PV fragment reads are 16B-aligned)
__global__ __launch_bounds__(512, 4) void attn_kernel(
    const unsigned short* __restrict__ h, const unsigned short* __restrict__ vT,
    const float* __restrict__ pbm_ptr, unsigned short* __restrict__ concat) {
  __shared__ __align__(16) unsigned short P[128][80];
  __shared__ __align__(16) unsigned short Ks[2][64][136];
  __shared__ __align__(16) float cArr[128];
  __shared__ __align__(16) float lArr[128];

  const int tid = threadIdx.x;
  const int lane = tid & 63;
  const int w = tid >> 6;   // 0..7
  const int lq = lane & 15;
  const int lg = lane >> 4;
  const int wr = w >> 2;    // 0..1
  const int wc = w & 3;     // 0..3
  const int bid = blockIdx.x;
  const int pair = bid >> 5;       // 0..15
  const int dcb = bid & 31;
  const int dc = dcb & 7;          // 0..7
  const int b = dcb >> 3;          // 0..3
  const float pbm = *pbm_ptr;
  const float SCALE = 0.08838834764831845f;

  const unsigned short* qb = h + (size_t)b * NSEQ * LDH;  // q cols 0..127
  const unsigned short* kb = qb + 128;                    // k cols 128..255
  const unsigned short* vtb = vT + (size_t)b * DM * NSEQ;

  auto stage = [&](int bufI, int kv0s) {
#pragma unroll
    for (int p = 0; p < 2; p++) {
      const int task = tid + p * 512;
      const int row = task >> 4;
      const int ch = task & 15;
      bf16x8 v = *reinterpret_cast<const bf16x8*>(
          kb + (size_t)(kv0s + row) * LDH + ch * 8);
      *reinterpret_cast<bf16x8*>(&Ks[bufI][row][ch * 8]) = v;
    }
  };

#pragma unroll 1
  for (int t = 0; t < 2; t++) {
    const int qt = (t == 0) ? pair : (31 - pair);
    const int N0 = qt * 128;
    const int qrow = N0 + w * 16 + lq;

    bf16x8 qf[4];
#pragma unroll
    for (int ks = 0; ks < 4; ks++)
      qf[ks] = *reinterpret_cast<const bf16x8*>(
          qb + (size_t)qrow * LDH + ks * 32 + lg * 8);

    f32x4 acc[4][2];
#pragma unroll
    for (int i = 0; i < 4; i++)
#pragma unroll
      for (int j = 0; j < 2; j++)
#pragma unroll
        for (int r = 0; r < 4; r++) acc[i][j][r] = 0.0f;
    float m = -1e30f, lsum = 0.0f;
    int buf = 0;

    stage(0, 0);
    __syncthreads();

    auto body = [&](int kv0, auto BIASC, auto MASKC) {
      constexpr bool BIAS = decltype(BIASC)::value;
      constexpr bool MASK = decltype(MASKC)::value;
      // ---- S phase: sa[sub] = K(16kv x 128) . Q(own 16 q) -- swapped mfma
      f32x4 sa[4];
#pragma unroll
      for (int sub = 0; sub < 4; sub++)
#pragma unroll
        for (int r = 0; r < 4; r++) sa[sub][r] = 0.0f;
#pragma unroll
      for (int ks = 0; ks < 4; ks++)
#pragma unroll
        for (int sub = 0; sub < 4; sub++) {
          bf16x8 kf = *reinterpret_cast<const bf16x8*>(
              &Ks[buf][sub * 16 + lq][ks * 32 + lg * 8]);
          sa[sub] =
              __builtin_amdgcn_mfma_f32_16x16x32_bf16(kf, qf[ks], sa[sub], 0, 0, 0);
        }
      // lane holds S[kv = kv0+sub*16+lg*4+r][q = qrow]
      float mloc = -1e30f;
#pragma unroll
      for (int sub = 0; sub < 4; sub++)
#pragma unroll
        for (int r = 0; r < 4; r++) {
          float s = sa[sub][r] * SCALE;
          if (BIAS) {
            const int kv = kv0 + sub * 16 + lg * 4 + r;
            if (MASK && kv > qrow) {
              s = -1e30f;
            } else {
              const float dn = (float)(kv - qrow) + pbm;
              s += 1.0f / (1.0f + __expf(-dn));
            }
          }
          sa[sub][r] = s;
          mloc = fmaxf(mloc, s);
        }
      mloc = fmaxf(mloc, __shfl_xor(mloc, 16));
      mloc = fmaxf(mloc, __shfl_xor(mloc, 32));
      float c = 1.0f;
      if (mloc > m + 8.0f) {  // defer-max: rescale only on large growth
        c = __expf(m - mloc);
        m = mloc;
      }
      float ps = 0.0f;
#pragma unroll
      for (int sub = 0; sub < 4; sub++) {
        bf16x4v pv;
#pragma unroll
        for (int r = 0; r < 4; r++) {
          const float p = __expf(sa[sub][r] - m);
          ps += p;
          pv[r] = (__bf16)p;
        }
        *reinterpret_cast<bf16x4v*>(&P[w * 16 + lq][sub * 16 + lg * 4]) = pv;
      }
      ps += __shfl_xor(ps, 16);
      ps += __shfl_xor(ps, 32);
      lsum = lsum * c + ps;
      if (lane < 16) cArr[w * 16 + lane] = c;
      if (kv0 < N0 + 64) stage(buf ^ 1, kv0 + 64);
      __syncthreads();

      // ---- PV phase
      bool need = false;
      f32x4 cv[4];
#pragma unroll
      for (int i = 0; i < 4; i++) {
        cv[i] = *reinterpret_cast<const f32x4*>(&cArr[wr * 64 + i * 16 + lg * 4]);
#pragma unroll
        for (int r = 0; r < 4; r++) need |= (cv[i][r] != 1.0f);
      }
      if (__any(need)) {
#pragma unroll
        for (int i = 0; i < 4; i++)
#pragma unroll
          for (int j = 0; j < 2; j++)
#pragma unroll
            for (int r = 0; r < 4; r++) acc[i][j][r] *= cv[i][r];
      }
      __builtin_amdgcn_s_setprio(1);
#pragma unroll
      for (int ks = 0; ks < 2; ks++) {
        bf16x8 pa[4];
#pragma unroll
        for (int i = 0; i < 4; i++)
          pa[i] = *reinterpret_cast<const bf16x8*>(
              &P[wr * 64 + i * 16 + lq][ks * 32 + lg * 8]);
#pragma unroll
        for (int j = 0; j < 2; j++) {
          bf16x8 bv = *reinterpret_cast<const bf16x8*>(
              vtb + (size_t)(dc * 128 + wc * 32 + j * 16 + lq) * NSEQ + kv0 +
              ks * 32 + lg * 8);
#pragma unroll
          for (int i = 0; i < 4; i++)
            acc[i][j] = __builtin_amdgcn_mfma_f32_16x16x32_bf16(pa[i], bv,
                                                                acc[i][j], 0, 0, 0);
        }
      }
      __builtin_amdgcn_s_setprio(0);
      __syncthreads();
      buf ^= 1;
    };

    for (int kv0 = 0; kv0 + 128 <= N0; kv0 += 64)
      body(kv0, std::false_type{}, std::false_type{});
    if (N0 >= 64) body(N0 - 64, std::true_type{}, std::false_type{});
    body(N0, std::true_type{}, std::true_type{});
    body(N0 + 64, std::true_type{}, std::true_type{});

    // ---- epilogue: normalize, write attn half of concat
    if (lane < 16) lArr[w * 16 + lane] = lsum;
    __syncthreads();
#pragma unroll
    for (int i = 0; i < 4; i++) {
      f32x4 lv = *reinterpret_cast<const f32x4*>(&lArr[wr * 64 + i * 16 + lg * 4]);
      f32x4 inv;
#pragma unroll
      for (int r = 0; r < 4; r++) inv[r] = 1.0f / lv[r];
#pragma unroll
      for (int j = 0; j < 2; j++)
#pragma unroll
        for (int r = 0; r < 4; r++) {
          const int grow = b * NSEQ + N0 + wr * 64 + i * 16 + lg * 4 + r;
          const int col = 1024 + dc * 128 + wc * 32 + j * 16 + lq;
          concat[(size_t)grow * 2048 + col] = f2bf(acc[i][j][r] * inv[r]);
        }
    }
    if (t == 0) __syncthreads();
  }
}

extern "C" void kernel_launch(void* const* d_in, const int* in_sizes, int n_in,
                              void* d_out, int out_size, void* d_ws,
                              size_t ws_size, hipStream_t stream) {
  (void)in_sizes;
  (void)n_in;
  (void)out_size;
  const float* x = (const float*)d_in[0];
  const float* expand = (const float*)d_in[1];
  const float* project = (const float*)d_in[2];
  const float* pbm = (const float*)d_in[3];
  float* out = (float*)d_out;

  const size_t H_BYTES = (size_t)16384 * LDH * 2;     // 142.6 MB
  const size_t CAT_BYTES = (size_t)16384 * 2048 * 2;  // 67.1 MB
  const size_t NX_BYTES = (size_t)16384 * DM * 2;     // 33.6 MB
  if (ws_size < H_BYTES + CAT_BYTES + NX_BYTES) return;

  char* ws = (char*)d_ws;
  unsigned short* h = (unsigned short*)ws;
  unsigned short* concat = (unsigned short*)(ws + H_BYTES);
  unsigned short* nx = (unsigned short*)(ws + H_BYTES + CAT_BYTES);
  unsigned short* vT = nx;  // nx dead after GEMM1; same region
  // expandT (4352x1024 bf16 = 8.9MB) aliases concat: dead before gate_local writes.
  unsigned short* expandT = concat;
  // projectT (1024x2048 bf16 = 4.2MB) aliases vT: written after attn consumes vT.
  unsigned short* projectT = vT;

  // 0a. expandT[n][k] = bf16(expand[k][n])   (K=1024 rows, N=4352 cols)
  tconv_kernel<<<dim3(68, 16), 256, 0, stream>>>(expand, expandT, 1024, LDH);
  // 1. LayerNorm
  ln_kernel<<<16384, 256, 0, stream>>>(x, nx);
  // 2. h = nx @ expandT^T  (M=16384, N=4352, K=1024)
  gemm_kernel<false><<<dim3(128 * 34), 256, 0, stream>>>(
      nx, DM, expandT, DM, (void*)h, LDH, DM, 34, nullptr);
  // 3. local half of concat (expandT dead from here)
  gate_local_kernel<<<8192, 256, 0, stream>>>(h, concat);
  // 4. v, transposed
  gate_vt_kernel<<<dim3(64, 16, 4), 256, 0, stream>>>(h, vT);
  // 5. attention -> concat[:, 1024:2048]
  attn_kernel<<<dim3(512), 512, 0, stream>>>(h, vT, pbm, concat);
  // 0b. projectT[n][k] = bf16(project[k][n])  (K=2048 rows, N=1024 cols); vT dead.
  tconv_kernel<<<dim3(16, 32), 256, 0, stream>>>(project, projectT, 2048, DM);
  // 6. out = x + concat @ projectT^T  (M=16384, N=1024, K=2048)
  gemm_kernel<true><<<dim3(128 * 8), 256, 0, stream>>>(
      concat, 2048, projectT, 2048, (void*)out, DM, 2048, 8, x);
}

// Round 6
// 494.868 us; speedup vs baseline: 2.2905x; 1.2140x over previous
//
#include <hip/hip_runtime.h>
#include <type_traits>

typedef __bf16 bf16x8 __attribute__((ext_vector_type(8)));
typedef __bf16 bf16x4v __attribute__((ext_vector_type(4)));
typedef float f32x4 __attribute__((ext_vector_type(4)));
typedef unsigned short u16x8 __attribute__((ext_vector_type(8)));
typedef unsigned short u16x4 __attribute__((ext_vector_type(4)));

#define NSEQ 4096
#define DM 1024
#define NBATCH 4

__device__ __forceinline__ unsigned short f2bf(float f) {
  unsigned u = __float_as_uint(f);
  u += 0x7FFFu + ((u >> 16) & 1u);
  return (unsigned short)(u >> 16);
}
__device__ __forceinline__ float bf2f(unsigned short h) {
  return __uint_as_float(((unsigned)h) << 16);
}
__device__ __forceinline__ float gelu_exact(float x) {
  return 0.5f * x * (1.0f + erff(x * 0.7071067811865475f));
}

// async global->LDS, 16B per lane; lds dst is wave-uniform base + lane*16
__device__ __forceinline__ void gload_lds16(const unsigned short* src,
                                            unsigned short* dst) {
  __builtin_amdgcn_global_load_lds(
      (const __attribute__((address_space(1))) unsigned int*)src,
      (__attribute__((address_space(3))) unsigned int*)dst, 16, 0, 0);
}

// ---------------- LayerNorm: x (f32) -> nx (bf16) ----------------
__global__ __launch_bounds__(256) void ln_kernel(const float* __restrict__ x,
                                                 unsigned short* __restrict__ nx) {
  const int row = blockIdx.x;
  const int tid = threadIdx.x;
  const float4 v = reinterpret_cast<const float4*>(x + (size_t)row * DM)[tid];
  float s = v.x + v.y + v.z + v.w;
  float q = v.x * v.x + v.y * v.y + v.z * v.z + v.w * v.w;
#pragma unroll
  for (int off = 32; off > 0; off >>= 1) {
    s += __shfl_down(s, off);
    q += __shfl_down(q, off);
  }
  __shared__ float ss[4], sq[4];
  if ((tid & 63) == 0) {
    ss[tid >> 6] = s;
    sq[tid >> 6] = q;
  }
  __syncthreads();
  const float ts = ss[0] + ss[1] + ss[2] + ss[3];
  const float tq = sq[0] + sq[1] + sq[2] + sq[3];
  const float mu = ts * (1.0f / DM);
  const float var = tq * (1.0f / DM) - mu * mu;
  const float rs = rsqrtf(var + 1e-5f);
  u16x4 o;
  o[0] = f2bf((v.x - mu) * rs);
  o[1] = f2bf((v.y - mu) * rs);
  o[2] = f2bf((v.z - mu) * rs);
  o[3] = f2bf((v.w - mu) * rs);
  *reinterpret_cast<u16x4*>(nx + (size_t)row * DM + tid * 4) = o;
}

// ---------------- transpose+convert: in f32 [K][N] -> out bf16 [N][K] -------------
__global__ __launch_bounds__(256) void tconv_kernel(const float* __restrict__ in,
                                                    unsigned short* __restrict__ out,
                                                    int K, int N) {
  __shared__ unsigned short tile[64][72];
  const int n0 = blockIdx.x * 64;
  const int k0 = blockIdx.y * 64;
  const int tid = threadIdx.x;
  const int lr = tid >> 4, lc = (tid & 15) * 4;
#pragma unroll
  for (int p = 0; p < 4; p++) {
    const int r = lr + p * 16;
    float4 v = *reinterpret_cast<const float4*>(in + (size_t)(k0 + r) * N + n0 + lc);
    tile[r][lc + 0] = f2bf(v.x);
    tile[r][lc + 1] = f2bf(v.y);
    tile[r][lc + 2] = f2bf(v.z);
    tile[r][lc + 3] = f2bf(v.w);
  }
  __syncthreads();
  const int nn = tid >> 2, kkg = (tid & 3) * 16;
  u16x8 o0, o1;
#pragma unroll
  for (int j = 0; j < 8; j++) {
    o0[j] = tile[kkg + j][nn];
    o1[j] = tile[kkg + 8 + j][nn];
  }
  unsigned short* dst = out + (size_t)(n0 + nn) * K + k0 + kkg;
  *reinterpret_cast<u16x8*>(dst) = o0;
  *reinterpret_cast<u16x8*>(dst + 8) = o1;
}

// ---------------- GEMM (m97 structure): C[M,N] = A[M,K] @ Bt[N,K] (both bf16) ------
template <bool FINAL>
__global__ __launch_bounds__(256, 4) void gemm_kernel(
    const unsigned short* __restrict__ A, int lda,
    const unsigned short* __restrict__ Bt, int ldb, void* __restrict__ Cv,
    int ldc, int K, int ntn, const float* __restrict__ X) {
  __shared__ unsigned short As[128][64];
  __shared__ unsigned short Bs[128][64];
  const int tid = threadIdx.x;
  const int bid = blockIdx.x;
  const int m0 = (bid / ntn) * 128;
  const int n0 = (bid % ntn) * 128;
  const int lane = tid & 63;
  const int w = tid >> 6;
  const int lr = lane & 15;
  const int lg = lane >> 4;
  const int wr = (w >> 1) * 64;
  const int wc = (w & 1) * 64;

  f32x4 acc[4][4];
#pragma unroll
  for (int i = 0; i < 4; i++)
#pragma unroll
    for (int j = 0; j < 4; j++)
#pragma unroll
      for (int r = 0; r < 4; r++) acc[i][j][r] = 0.0f;

  for (int k0 = 0; k0 < K; k0 += 64) {
#pragma unroll
    for (int j = 0; j < 4; j++) {
      const int boff = w * 4096 + j * 1024 + lane * 16;
      const int row = boff >> 7;
      const int col = (boff & 127) >> 1;
      gload_lds16(A + (size_t)(m0 + row) * lda + k0 + col,
                  &As[0][0] + (boff - lane * 16) / 2);
    }
#pragma unroll
    for (int j = 0; j < 4; j++) {
      const int boff = w * 4096 + j * 1024 + lane * 16;
      const int row = boff >> 7;
      const int col = (boff & 127) >> 1;
      gload_lds16(Bt + (size_t)(n0 + row) * ldb + k0 + col,
                  &Bs[0][0] + (boff - lane * 16) / 2);
    }
    __syncthreads();
#pragma unroll
    for (int kk = 0; kk < 64; kk += 32) {
      bf16x8 af[4], bfr[4];
#pragma unroll
      for (int i = 0; i < 4; i++)
        af[i] =
            *reinterpret_cast<const bf16x8*>(&As[wr + i * 16 + lr][kk + lg * 8]);
#pragma unroll
      for (int j = 0; j < 4; j++)
        bfr[j] =
            *reinterpret_cast<const bf16x8*>(&Bs[wc + j * 16 + lr][kk + lg * 8]);
#pragma unroll
      for (int i = 0; i < 4; i++)
#pragma unroll
        for (int j = 0; j < 4; j++)
          acc[i][j] = __builtin_amdgcn_mfma_f32_16x16x32_bf16(af[i], bfr[j],
                                                              acc[i][j], 0, 0, 0);
    }
    __syncthreads();
  }

  if (FINAL) {
    float* C = reinterpret_cast<float*>(Cv);
#pragma unroll
    for (int i = 0; i < 4; i++)
#pragma unroll
      for (int j = 0; j < 4; j++)
#pragma unroll
        for (int r = 0; r < 4; r++) {
          const int row = m0 + wr + i * 16 + lg * 4 + r;
          const int col = n0 + wc + j * 16 + lr;
          const size_t off = (size_t)row * ldc + col;
          C[off] = X[off] + acc[i][j][r];
        }
  } else {
    unsigned short* C = reinterpret_cast<unsigned short*>(Cv);
#pragma unroll
    for (int i = 0; i < 4; i++)
#pragma unroll
      for (int j = 0; j < 4; j++)
#pragma unroll
        for (int r = 0; r < 4; r++) {
          const int row = m0 + wr + i * 16 + lg * 4 + r;
          const int col = n0 + wc + j * 16 + lr;
          C[(size_t)row * ldc + col] = f2bf(acc[i][j][r]);
        }
  }
}

// ---------------- gate: local = lin * gelu(pg) -> concat[:, 0:1024] ----------------
// gateH layout per row (4096): [linear 0..2047 | pre_gelu 2048..4095]
__global__ __launch_bounds__(256) void gate_local_kernel(
    const unsigned short* __restrict__ gateH, unsigned short* __restrict__ concat) {
  const int idx = blockIdx.x * 256 + threadIdx.x;
  const int row = idx >> 7;
  const int cg = idx & 127;
  const unsigned short* hr = gateH + (size_t)row * 4096;
  u16x8 lin = *reinterpret_cast<const u16x8*>(hr + cg * 8);
  u16x8 pg = *reinterpret_cast<const u16x8*>(hr + 2048 + cg * 8);
  u16x8 o;
#pragma unroll
  for (int j = 0; j < 8; j++) {
    const float l = bf2f(lin[j]);
    const float g = gelu_exact(bf2f(pg[j]));
    o[j] = f2bf(l * g);
  }
  *reinterpret_cast<u16x8*>(concat + (size_t)row * 2048 + cg * 8) = o;
}

// ---------------- gate: v = lin * gelu(pg), stored transposed vT[b][d][n] -------------
__global__ __launch_bounds__(256) void gate_vt_kernel(
    const unsigned short* __restrict__ gateH, unsigned short* __restrict__ vT) {
  __shared__ unsigned short tbuf[64][72];
  const int n0 = blockIdx.x * 64;
  const int d0 = blockIdx.y * 64;
  const int b = blockIdx.z;
  const int tid = threadIdx.x;
#pragma unroll
  for (int p = 0; p < 2; p++) {
    const int r = p * 32 + (tid >> 3);
    const int cg = tid & 7;
    const unsigned short* hr = gateH + (size_t)(b * NSEQ + n0 + r) * 4096;
    u16x8 lin = *reinterpret_cast<const u16x8*>(hr + 1024 + d0 + cg * 8);
    u16x8 pg = *reinterpret_cast<const u16x8*>(hr + 3072 + d0 + cg * 8);
    u16x8 o;
#pragma unroll
    for (int j = 0; j < 8; j++) {
      const float l = bf2f(lin[j]);
      const float g = gelu_exact(bf2f(pg[j]));
      o[j] = f2bf(l * g);
    }
    *reinterpret_cast<u16x8*>(&tbuf[r][cg * 8]) = o;
  }
  __syncthreads();
#pragma unroll
  for (int p = 0; p < 2; p++) {
    const int d = p * 32 + (tid >> 3);
    const int ng = tid & 7;
    u16x8 o;
#pragma unroll
    for (int j = 0; j < 8; j++) o[j] = tbuf[ng * 8 + j][d];
    *reinterpret_cast<u16x8*>(vT + (size_t)(b * DM + d0 + d) * NSEQ + n0 +
                              ng * 8) = o;
  }
}

// ---------------- P kernel: one causal 128x128 tile per block --------------------
// P = exp(S*scale + sigmoid-bias) with NO max subtraction (S*scale+1 <= ~4 by
// construction: LN'd x through the given weight scales -> exp is safe).
// Writes P bf16 (causal-packed layout) and atomicAdds row sums l (f32).
// qk layout: [b*4096 + n][256]: q = cols 0..127, k = cols 128..255.
#define P_TILE 16384           // 128*128
#define P_PER_B 8650752        // 528 tiles * 16384
__global__ __launch_bounds__(512, 4) void pk_kernel(
    const unsigned short* __restrict__ qk, const float* __restrict__ pbm_ptr,
    unsigned short* __restrict__ P, float* __restrict__ l) {
  __shared__ unsigned short Ks[128][136];
  const int tid = threadIdx.x;
  const int lane = tid & 63;
  const int w = tid >> 6;
  const int lq = lane & 15;
  const int lg = lane >> 4;
  const int bid = blockIdx.x;
  const int b = bid / 528;
  const int t = bid - b * 528;
  int qt = (int)((sqrtf((float)(8 * t + 1)) - 1.0f) * 0.5f);
  while ((qt + 1) * (qt + 2) / 2 <= t) ++qt;
  while (qt * (qt + 1) / 2 > t) --qt;
  const int kt = t - qt * (qt + 1) / 2;
  const float pbm = *pbm_ptr;
  const float SCALE = 0.08838834764831845f;

  const unsigned short* qb = qk + (size_t)b * NSEQ * 256;

  // stage K tile [128 kv][128 d]
#pragma unroll
  for (int p = 0; p < 4; p++) {
    const int task = tid + p * 512;
    const int row = task >> 4;
    const int ch = task & 15;
    bf16x8 v = *reinterpret_cast<const bf16x8*>(
        qb + (size_t)(kt * 128 + row) * 256 + 128 + ch * 8);
    *reinterpret_cast<bf16x8*>(&Ks[row][ch * 8]) = v;
  }
  // q fragments: wave w owns q rows qt*128 + w*16 + lq
  const int qloc = w * 16 + lq;
  bf16x8 qf[4];
#pragma unroll
  for (int ks = 0; ks < 4; ks++)
    qf[ks] = *reinterpret_cast<const bf16x8*>(
        qb + (size_t)(qt * 128 + qloc) * 256 + ks * 32 + lg * 8);
  __syncthreads();

  f32x4 sa[8];
#pragma unroll
  for (int sub = 0; sub < 8; sub++)
#pragma unroll
    for (int r = 0; r < 4; r++) sa[sub][r] = 0.0f;
#pragma unroll
  for (int ks = 0; ks < 4; ks++)
#pragma unroll
    for (int sub = 0; sub < 8; sub++) {
      bf16x8 kf =
          *reinterpret_cast<const bf16x8*>(&Ks[sub * 16 + lq][ks * 32 + lg * 8]);
      sa[sub] = __builtin_amdgcn_mfma_f32_16x16x32_bf16(kf, qf[ks], sa[sub], 0, 0, 0);
    }
  // lane holds S[kv = kt*128 + sub*16 + lg*4 + r][q = qt*128 + qloc]
  const size_t KL = (size_t)(qt + 1) * 128;
  unsigned short* Prow = P + (size_t)b * P_PER_B +
                         (size_t)(qt * (qt + 1) / 2) * P_TILE + (size_t)qloc * KL +
                         kt * 128;
  float ps = 0.0f;
  const bool diag = (kt == qt);
#pragma unroll
  for (int sub = 0; sub < 8; sub++) {
    bf16x4v pv;
#pragma unroll
    for (int r = 0; r < 4; r++) {
      const int kvloc = sub * 16 + lg * 4 + r;
      float p;
      if (diag && kvloc > qloc) {
        p = 0.0f;
      } else {
        const float dn = (float)((kt - qt) * 128 + kvloc - qloc) + pbm;
        const float s = sa[sub][r] * SCALE + 1.0f / (1.0f + __expf(-dn));
        p = __expf(s);
      }
      ps += p;
      pv[r] = (__bf16)p;
    }
    *reinterpret_cast<bf16x4v*>(Prow + sub * 16 + lg * 4) = pv;
  }
  ps += __shfl_xor(ps, 16);
  ps += __shfl_xor(ps, 32);
  if (lane < 16) atomicAdd(&l[b * NSEQ + qt * 128 + w * 16 + lane], ps);
}

// ---------------- PV kernel: O[128, 128] = P[128, KL] @ vT^T, /l, -> concat ------
__global__ __launch_bounds__(256, 4) void pv_kernel(
    const unsigned short* __restrict__ P, const unsigned short* __restrict__ vT,
    const float* __restrict__ l, unsigned short* __restrict__ concat) {
  __shared__ unsigned short As[128][64];
  __shared__ unsigned short Bs[128][64];
  const int tid = threadIdx.x;
  const int bid = blockIdx.x;
  const int qt = 31 - (bid >> 5);  // heavy tiles dispatched first
  const int rest = bid & 31;
  const int b = rest >> 3;
  const int nt = rest & 7;
  const int KL = (qt + 1) * 128;
  const unsigned short* A =
      P + (size_t)b * P_PER_B + (size_t)(qt * (qt + 1) / 2) * P_TILE;
  const unsigned short* Bt = vT + (size_t)b * DM * NSEQ;
  const int n0 = nt * 128;
  const int lane = tid & 63;
  const int w = tid >> 6;
  const int lr = lane & 15;
  const int lg = lane >> 4;
  const int wr = (w >> 1) * 64;
  const int wc = (w & 1) * 64;

  f32x4 acc[4][4];
#pragma unroll
  for (int i = 0; i < 4; i++)
#pragma unroll
    for (int j = 0; j < 4; j++)
#pragma unroll
      for (int r = 0; r < 4; r++) acc[i][j][r] = 0.0f;

  for (int k0 = 0; k0 < KL; k0 += 64) {
#pragma unroll
    for (int j = 0; j < 4; j++) {
      const int boff = w * 4096 + j * 1024 + lane * 16;
      const int row = boff >> 7;
      const int col = (boff & 127) >> 1;
      gload_lds16(A + (size_t)row * KL + k0 + col,
                  &As[0][0] + (boff - lane * 16) / 2);
    }
#pragma unroll
    for (int j = 0; j < 4; j++) {
      const int boff = w * 4096 + j * 1024 + lane * 16;
      const int row = boff >> 7;
      const int col = (boff & 127) >> 1;
      gload_lds16(Bt + (size_t)(n0 + row) * NSEQ + k0 + col,
                  &Bs[0][0] + (boff - lane * 16) / 2);
    }
    __syncthreads();
#pragma unroll
    for (int kk = 0; kk < 64; kk += 32) {
      bf16x8 af[4], bfr[4];
#pragma unroll
      for (int i = 0; i < 4; i++)
        af[i] =
            *reinterpret_cast<const bf16x8*>(&As[wr + i * 16 + lr][kk + lg * 8]);
#pragma unroll
      for (int j = 0; j < 4; j++)
        bfr[j] =
            *reinterpret_cast<const bf16x8*>(&Bs[wc + j * 16 + lr][kk + lg * 8]);
#pragma unroll
      for (int i = 0; i < 4; i++)
#pragma unroll
        for (int j = 0; j < 4; j++)
          acc[i][j] = __builtin_amdgcn_mfma_f32_16x16x32_bf16(af[i], bfr[j],
                                                              acc[i][j], 0, 0, 0);
    }
    __syncthreads();
  }

  const float* lb = l + b * NSEQ + qt * 128;
#pragma unroll
  for (int i = 0; i < 4; i++) {
    f32x4 lv = *reinterpret_cast<const f32x4*>(&lb[wr + i * 16 + lg * 4]);
    f32x4 inv;
#pragma unroll
    for (int r = 0; r < 4; r++) inv[r] = 1.0f / lv[r];
#pragma unroll
    for (int j = 0; j < 4; j++)
#pragma unroll
      for (int r = 0; r < 4; r++) {
        const int grow = b * NSEQ + qt * 128 + wr + i * 16 + lg * 4 + r;
        const int col = 1024 + n0 + wc + j * 16 + lr;
        concat[(size_t)grow * 2048 + col] = f2bf(acc[i][j][r] * inv[r]);
      }
  }
}

extern "C" void kernel_launch(void* const* d_in, const int* in_sizes, int n_in,
                              void* d_out, int out_size, void* d_ws,
                              size_t ws_size, hipStream_t stream) {
  (void)in_sizes;
  (void)n_in;
  (void)out_size;
  const float* x = (const float*)d_in[0];
  const float* expand = (const float*)d_in[1];
  const float* project = (const float*)d_in[2];
  const float* pbm = (const float*)d_in[3];
  float* out = (float*)d_out;

  // Region map (243.3 MB total, unchanged from round 5):
  // R0: qk      [16384][256] bf16   =   8.4 MB
  // R1: gateH   [16384][4096] bf16  = 134.2 MB  (P 69.2MB + l 64KB alias after gates)
  // R2: concat  [16384][2048] bf16  =  67.1 MB  (expandT 8.9MB aliases pre-gate)
  // R3: nx      [16384][1024] bf16  =  33.6 MB  (vT aliases post-GEMM1; projectT post-PV)
  const size_t QK_BYTES = (size_t)16384 * 256 * 2;
  const size_t GH_BYTES = (size_t)16384 * 4096 * 2;
  const size_t CAT_BYTES = (size_t)16384 * 2048 * 2;
  const size_t NX_BYTES = (size_t)16384 * DM * 2;
  const size_t P_BYTES = (size_t)NBATCH * P_PER_B * 2;  // 69.2 MB
  if (ws_size < QK_BYTES + GH_BYTES + CAT_BYTES + NX_BYTES) return;

  char* ws = (char*)d_ws;
  unsigned short* qk = (unsigned short*)ws;
  unsigned short* gateH = (unsigned short*)(ws + QK_BYTES);
  unsigned short* concat = (unsigned short*)(ws + QK_BYTES + GH_BYTES);
  unsigned short* nx = (unsigned short*)(ws + QK_BYTES + GH_BYTES + CAT_BYTES);
  unsigned short* vT = nx;
  unsigned short* projectT = nx;
  unsigned short* expandT = concat;
  unsigned short* P = gateH;  // aliases gateH after gates consume it
  float* l = (float*)(ws + QK_BYTES + P_BYTES);  // after P within R1

  // 0a. expandT[n][k] = bf16(expand[k][n])
  tconv_kernel<<<dim3(68, 16), 256, 0, stream>>>(expand, expandT, 1024, 4352);
  // 1. LayerNorm
  ln_kernel<<<16384, 256, 0, stream>>>(x, nx);
  // 2a. qk = nx @ expandT[0:256]^T
  gemm_kernel<false><<<dim3(128 * 2), 256, 0, stream>>>(
      nx, DM, expandT, DM, (void*)qk, 256, DM, 2, nullptr);
  // 2b. gateH = nx @ expandT[256:4352]^T
  gemm_kernel<false><<<dim3(128 * 32), 256, 0, stream>>>(
      nx, DM, expandT + (size_t)256 * DM, DM, (void*)gateH, 4096, DM, 32, nullptr);
  // 3. local half of concat
  gate_local_kernel<<<8192, 256, 0, stream>>>(gateH, concat);
  // 4. v transposed (nx dead)
  gate_vt_kernel<<<dim3(64, 16, 4), 256, 0, stream>>>(gateH, vT);
  // 5. P = softmax numerator (gateH dead -> P aliases it); l zeroed first
  hipMemsetAsync(l, 0, (size_t)NBATCH * NSEQ * 4, stream);
  pk_kernel<<<dim3(NBATCH * 528), 512, 0, stream>>>(qk, pbm, P, l);
  // 6. attn = (P @ V) / l -> concat[:, 1024:2048]
  pv_kernel<<<dim3(1024), 256, 0, stream>>>(P, vT, l, concat);
  // 7. projectT (vT dead)
  tconv_kernel<<<dim3(16, 32), 256, 0, stream>>>(project, projectT, 2048, DM);
  // 8. out = x + concat @ projectT^T
  gemm_kernel<true><<<dim3(128 * 8), 256, 0, stream>>>(
      concat, 2048, projectT, 2048, (void*)out, DM, 2048, 8, x);
}

// Round 7
// 493.999 us; speedup vs baseline: 2.2946x; 1.0018x over previous
//
#include <hip/hip_runtime.h>
#include <type_traits>

typedef __bf16 bf16x8 __attribute__((ext_vector_type(8)));
typedef __bf16 bf16x4v __attribute__((ext_vector_type(4)));
typedef float f32x4 __attribute__((ext_vector_type(4)));
typedef unsigned short u16x8 __attribute__((ext_vector_type(8)));
typedef unsigned short u16x4 __attribute__((ext_vector_type(4)));

#define NSEQ 4096
#define DM 1024
#define NBATCH 4

__device__ __forceinline__ unsigned short f2bf(float f) {
  unsigned u = __float_as_uint(f);
  u += 0x7FFFu + ((u >> 16) & 1u);
  return (unsigned short)(u >> 16);
}
__device__ __forceinline__ float bf2f(unsigned short h) {
  return __uint_as_float(((unsigned)h) << 16);
}
__device__ __forceinline__ float gelu_exact(float x) {
  return 0.5f * x * (1.0f + erff(x * 0.7071067811865475f));
}

// async global->LDS, 16B per lane; lds dst is wave-uniform base + lane*16
__device__ __forceinline__ void gload_lds16(const unsigned short* src,
                                            unsigned short* dst) {
  __builtin_amdgcn_global_load_lds(
      (const __attribute__((address_space(1))) unsigned int*)src,
      (__attribute__((address_space(3))) unsigned int*)dst, 16, 0, 0);
}

#define BAR() asm volatile("s_barrier" ::: "memory")
#define VMCNT8() asm volatile("s_waitcnt vmcnt(8)" ::: "memory")

// ---------------- LayerNorm: x (f32) -> nx (bf16) ----------------
__global__ __launch_bounds__(256) void ln_kernel(const float* __restrict__ x,
                                                 unsigned short* __restrict__ nx) {
  const int row = blockIdx.x;
  const int tid = threadIdx.x;
  const float4 v = reinterpret_cast<const float4*>(x + (size_t)row * DM)[tid];
  float s = v.x + v.y + v.z + v.w;
  float q = v.x * v.x + v.y * v.y + v.z * v.z + v.w * v.w;
#pragma unroll
  for (int off = 32; off > 0; off >>= 1) {
    s += __shfl_down(s, off);
    q += __shfl_down(q, off);
  }
  __shared__ float ss[4], sq[4];
  if ((tid & 63) == 0) {
    ss[tid >> 6] = s;
    sq[tid >> 6] = q;
  }
  __syncthreads();
  const float ts = ss[0] + ss[1] + ss[2] + ss[3];
  const float tq = sq[0] + sq[1] + sq[2] + sq[3];
  const float mu = ts * (1.0f / DM);
  const float var = tq * (1.0f / DM) - mu * mu;
  const float rs = rsqrtf(var + 1e-5f);
  u16x4 o;
  o[0] = f2bf((v.x - mu) * rs);
  o[1] = f2bf((v.y - mu) * rs);
  o[2] = f2bf((v.z - mu) * rs);
  o[3] = f2bf((v.w - mu) * rs);
  *reinterpret_cast<u16x4*>(nx + (size_t)row * DM + tid * 4) = o;
}

// ---------------- transpose+convert: in f32 [K][N] -> out bf16 [N][K] -------------
__global__ __launch_bounds__(256) void tconv_kernel(const float* __restrict__ in,
                                                    unsigned short* __restrict__ out,
                                                    int K, int N) {
  __shared__ unsigned short tile[64][72];
  const int n0 = blockIdx.x * 64;
  const int k0 = blockIdx.y * 64;
  const int tid = threadIdx.x;
  const int lr = tid >> 4, lc = (tid & 15) * 4;
#pragma unroll
  for (int p = 0; p < 4; p++) {
    const int r = lr + p * 16;
    float4 v = *reinterpret_cast<const float4*>(in + (size_t)(k0 + r) * N + n0 + lc);
    tile[r][lc + 0] = f2bf(v.x);
    tile[r][lc + 1] = f2bf(v.y);
    tile[r][lc + 2] = f2bf(v.z);
    tile[r][lc + 3] = f2bf(v.w);
  }
  __syncthreads();
  const int nn = tid >> 2, kkg = (tid & 3) * 16;
  u16x8 o0, o1;
#pragma unroll
  for (int j = 0; j < 8; j++) {
    o0[j] = tile[kkg + j][nn];
    o1[j] = tile[kkg + 8 + j][nn];
  }
  unsigned short* dst = out + (size_t)(n0 + nn) * K + k0 + kkg;
  *reinterpret_cast<u16x8*>(dst) = o0;
  *reinterpret_cast<u16x8*>(dst + 8) = o1;
}

// ---------------- 256x256 8-phase GEMM: C[M,N] = A[M,K] @ Bt[N,K] (bf16) ----------
// 512 thr = 8 waves (2M x 4N), BK=64, LDS 128 KiB as [dbuf][khalf][256][32].
// 64B row stride => frag reads are bank-conflict-free without swizzle.
// Stage order: ph0->A-kh1(T+1), ph1->B-kh1(T+1), ph2->A-kh0(T+2), ph3->B-kh0(T+2).
// vmcnt(8) after ph1/ph3 stage issues: guarded loads are exactly 8 issues old.
template <bool FINAL>
__global__ __launch_bounds__(512, 2) void gemm256_kernel(
    const unsigned short* __restrict__ A, int lda,
    const unsigned short* __restrict__ Bt, int ldb, void* __restrict__ Cv,
    int ldc, int K, int ntn, const float* __restrict__ X) {
  __shared__ unsigned short Ah[2][2][8192];  // [dbuf][khalf][row*32+k]
  __shared__ unsigned short Bh[2][2][8192];
  const int tid = threadIdx.x;
  const int lane = tid & 63;
  const int w = tid >> 6;
  const int lq = lane & 15;
  const int lg = lane >> 4;
  const int wm = w >> 2;  // 0..1
  const int wn = w & 3;   // 0..3
  const int bid = blockIdx.x;
  const int m0 = (bid / ntn) * 256;
  const int n0 = (bid % ntn) * 256;
  const int nk = K >> 6;

  // staging geometry: chunk g = j*512 + w*64 + lane; row = g>>2, kc = g&3
  const int g0 = w * 64 + lane;
  const int rowS = g0 >> 2;
  const int kcS = (g0 & 3) * 8;
  const unsigned short* Asrc = A + (size_t)(m0 + rowS) * lda + kcS;
  const unsigned short* Bsrc = Bt + (size_t)(n0 + rowS) * ldb + kcS;
  const size_t ldaj = (size_t)128 * lda;
  const size_t ldbj = (size_t)128 * ldb;
  const int dstW = w * 64 * 8;  // ushort offset of this wave's slice (j=0)

  auto stageA = [&](int db, int kh, int kt2) {
    if (kt2 < nk) {
      const unsigned short* s = Asrc + (size_t)kt2 * 64 + kh * 32;
      unsigned short* d = &Ah[db][kh][0] + dstW;
      gload_lds16(s, d);
      gload_lds16(s + ldaj, d + 4096);
    }
  };
  auto stageB = [&](int db, int kh, int kt2) {
    if (kt2 < nk) {
      const unsigned short* s = Bsrc + (size_t)kt2 * 64 + kh * 32;
      unsigned short* d = &Bh[db][kh][0] + dstW;
      gload_lds16(s, d);
      gload_lds16(s + ldbj, d + 4096);
    }
  };

  f32x4 acc[8][4];
#pragma unroll
  for (int i = 0; i < 8; i++)
#pragma unroll
    for (int j = 0; j < 4; j++)
#pragma unroll
      for (int r = 0; r < 4; r++) acc[i][j][r] = 0.0f;

  // prologue: A0,B0,A1,B1 of tile 0; A0,B0 of tile 1 (12 loads)
  stageA(0, 0, 0);
  stageB(0, 0, 0);
  stageA(0, 1, 0);
  stageB(0, 1, 0);
  stageA(1, 0, 1);
  stageB(1, 0, 1);
  VMCNT8();
  BAR();

  const int aBase = wm * 128;
  const int bBase = wn * 64;

#pragma unroll 1
  for (int kt = 0; kt < nk; ++kt) {
    const int buf = kt & 1;
    bf16x8 af[4], bf0[4], bf1[4];

    // ---- phase 0: kh0, rows 0-63; stage A-kh1(kt+1)
#pragma unroll
    for (int i = 0; i < 4; i++)
      af[i] = *reinterpret_cast<const bf16x8*>(
          &Ah[buf][0][(aBase + i * 16 + lq) * 32 + lg * 8]);
#pragma unroll
    for (int j = 0; j < 4; j++)
      bf0[j] = *reinterpret_cast<const bf16x8*>(
          &Bh[buf][0][(bBase + j * 16 + lq) * 32 + lg * 8]);
    stageA(buf ^ 1, 1, kt + 1);
    BAR();
    __builtin_amdgcn_s_setprio(1);
#pragma unroll
    for (int i = 0; i < 4; i++)
#pragma unroll
      for (int j = 0; j < 4; j++)
        acc[i][j] =
            __builtin_amdgcn_mfma_f32_16x16x32_bf16(af[i], bf0[j], acc[i][j], 0, 0, 0);
    __builtin_amdgcn_s_setprio(0);
    BAR();

    // ---- phase 1: kh0, rows 64-127; stage B-kh1(kt+1); vmcnt(8)
#pragma unroll
    for (int i = 0; i < 4; i++)
      af[i] = *reinterpret_cast<const bf16x8*>(
          &Ah[buf][0][(aBase + 64 + i * 16 + lq) * 32 + lg * 8]);
    stageB(buf ^ 1, 1, kt + 1);
    VMCNT8();
    BAR();
    __builtin_amdgcn_s_setprio(1);
#pragma unroll
    for (int i = 0; i < 4; i++)
#pragma unroll
      for (int j = 0; j < 4; j++)
        acc[4 + i][j] = __builtin_amdgcn_mfma_f32_16x16x32_bf16(af[i], bf0[j],
                                                                acc[4 + i][j], 0, 0, 0);
    __builtin_amdgcn_s_setprio(0);
    BAR();

    // ---- phase 2: kh1, rows 0-63; stage A-kh0(kt+2)
#pragma unroll
    for (int i = 0; i < 4; i++)
      af[i] = *reinterpret_cast<const bf16x8*>(
          &Ah[buf][1][(aBase + i * 16 + lq) * 32 + lg * 8]);
#pragma unroll
    for (int j = 0; j < 4; j++)
      bf1[j] = *reinterpret_cast<const bf16x8*>(
          &Bh[buf][1][(bBase + j * 16 + lq) * 32 + lg * 8]);
    stageA(buf, 0, kt + 2);
    BAR();
    __builtin_amdgcn_s_setprio(1);
#pragma unroll
    for (int i = 0; i < 4; i++)
#pragma unroll
      for (int j = 0; j < 4; j++)
        acc[i][j] =
            __builtin_amdgcn_mfma_f32_16x16x32_bf16(af[i], bf1[j], acc[i][j], 0, 0, 0);
    __builtin_amdgcn_s_setprio(0);
    BAR();

    // ---- phase 3: kh1, rows 64-127; stage B-kh0(kt+2); vmcnt(8)
#pragma unroll
    for (int i = 0; i < 4; i++)
      af[i] = *reinterpret_cast<const bf16x8*>(
          &Ah[buf][1][(aBase + 64 + i * 16 + lq) * 32 + lg * 8]);
    stageB(buf, 0, kt + 2);
    VMCNT8();
    BAR();
    __builtin_amdgcn_s_setprio(1);
#pragma unroll
    for (int i = 0; i < 4; i++)
#pragma unroll
      for (int j = 0; j < 4; j++)
        acc[4 + i][j] = __builtin_amdgcn_mfma_f32_16x16x32_bf16(af[i], bf1[j],
                                                                acc[4 + i][j], 0, 0, 0);
    __builtin_amdgcn_s_setprio(0);
    BAR();
  }

  if (FINAL) {
    float* C = reinterpret_cast<float*>(Cv);
#pragma unroll
    for (int I = 0; I < 8; I++)
#pragma unroll
      for (int j = 0; j < 4; j++)
#pragma unroll
        for (int r = 0; r < 4; r++) {
          const int row = m0 + wm * 128 + I * 16 + lg * 4 + r;
          const int col = n0 + wn * 64 + j * 16 + lq;
          const size_t off = (size_t)row * ldc + col;
          C[off] = X[off] + acc[I][j][r];
        }
  } else {
    unsigned short* C = reinterpret_cast<unsigned short*>(Cv);
#pragma unroll
    for (int I = 0; I < 8; I++)
#pragma unroll
      for (int j = 0; j < 4; j++)
#pragma unroll
        for (int r = 0; r < 4; r++) {
          const int row = m0 + wm * 128 + I * 16 + lg * 4 + r;
          const int col = n0 + wn * 64 + j * 16 + lq;
          C[(size_t)row * ldc + col] = f2bf(acc[I][j][r]);
        }
  }
}

// ---------------- gate: local = lin * gelu(pg) -> concat[:, 0:1024] ----------------
__global__ __launch_bounds__(256) void gate_local_kernel(
    const unsigned short* __restrict__ gateH, unsigned short* __restrict__ concat) {
  const int idx = blockIdx.x * 256 + threadIdx.x;
  const int row = idx >> 7;
  const int cg = idx & 127;
  const unsigned short* hr = gateH + (size_t)row * 4096;
  u16x8 lin = *reinterpret_cast<const u16x8*>(hr + cg * 8);
  u16x8 pg = *reinterpret_cast<const u16x8*>(hr + 2048 + cg * 8);
  u16x8 o;
#pragma unroll
  for (int j = 0; j < 8; j++) {
    const float l = bf2f(lin[j]);
    const float g = gelu_exact(bf2f(pg[j]));
    o[j] = f2bf(l * g);
  }
  *reinterpret_cast<u16x8*>(concat + (size_t)row * 2048 + cg * 8) = o;
}

// ---------------- gate: v = lin * gelu(pg), stored transposed vT[b][d][n] -------------
__global__ __launch_bounds__(256) void gate_vt_kernel(
    const unsigned short* __restrict__ gateH, unsigned short* __restrict__ vT) {
  __shared__ unsigned short tbuf[64][72];
  const int n0 = blockIdx.x * 64;
  const int d0 = blockIdx.y * 64;
  const int b = blockIdx.z;
  const int tid = threadIdx.x;
#pragma unroll
  for (int p = 0; p < 2; p++) {
    const int r = p * 32 + (tid >> 3);
    const int cg = tid & 7;
    const unsigned short* hr = gateH + (size_t)(b * NSEQ + n0 + r) * 4096;
    u16x8 lin = *reinterpret_cast<const u16x8*>(hr + 1024 + d0 + cg * 8);
    u16x8 pg = *reinterpret_cast<const u16x8*>(hr + 3072 + d0 + cg * 8);
    u16x8 o;
#pragma unroll
    for (int j = 0; j < 8; j++) {
      const float l = bf2f(lin[j]);
      const float g = gelu_exact(bf2f(pg[j]));
      o[j] = f2bf(l * g);
    }
    *reinterpret_cast<u16x8*>(&tbuf[r][cg * 8]) = o;
  }
  __syncthreads();
#pragma unroll
  for (int p = 0; p < 2; p++) {
    const int d = p * 32 + (tid >> 3);
    const int ng = tid & 7;
    u16x8 o;
#pragma unroll
    for (int j = 0; j < 8; j++) o[j] = tbuf[ng * 8 + j][d];
    *reinterpret_cast<u16x8*>(vT + (size_t)(b * DM + d0 + d) * NSEQ + n0 +
                              ng * 8) = o;
  }
}

// ---------------- P kernel: one causal 128x128 tile per block --------------------
#define P_TILE 16384           // 128*128
#define P_PER_B 8650752        // 528 tiles * 16384
__global__ __launch_bounds__(512, 4) void pk_kernel(
    const unsigned short* __restrict__ qk, const float* __restrict__ pbm_ptr,
    unsigned short* __restrict__ P, float* __restrict__ l) {
  __shared__ unsigned short Ks[128][136];
  const int tid = threadIdx.x;
  const int lane = tid & 63;
  const int w = tid >> 6;
  const int lq = lane & 15;
  const int lg = lane >> 4;
  const int bid = blockIdx.x;
  const int b = bid / 528;
  const int t = bid - b * 528;
  int qt = (int)((sqrtf((float)(8 * t + 1)) - 1.0f) * 0.5f);
  while ((qt + 1) * (qt + 2) / 2 <= t) ++qt;
  while (qt * (qt + 1) / 2 > t) --qt;
  const int kt = t - qt * (qt + 1) / 2;
  const float pbm = *pbm_ptr;
  const float SCALE = 0.08838834764831845f;

  const unsigned short* qb = qk + (size_t)b * NSEQ * 256;

#pragma unroll
  for (int p = 0; p < 4; p++) {
    const int task = tid + p * 512;
    const int row = task >> 4;
    const int ch = task & 15;
    bf16x8 v = *reinterpret_cast<const bf16x8*>(
        qb + (size_t)(kt * 128 + row) * 256 + 128 + ch * 8);
    *reinterpret_cast<bf16x8*>(&Ks[row][ch * 8]) = v;
  }
  const int qloc = w * 16 + lq;
  bf16x8 qf[4];
#pragma unroll
  for (int ks = 0; ks < 4; ks++)
    qf[ks] = *reinterpret_cast<const bf16x8*>(
        qb + (size_t)(qt * 128 + qloc) * 256 + ks * 32 + lg * 8);
  __syncthreads();

  f32x4 sa[8];
#pragma unroll
  for (int sub = 0; sub < 8; sub++)
#pragma unroll
    for (int r = 0; r < 4; r++) sa[sub][r] = 0.0f;
#pragma unroll
  for (int ks = 0; ks < 4; ks++)
#pragma unroll
    for (int sub = 0; sub < 8; sub++) {
      bf16x8 kf =
          *reinterpret_cast<const bf16x8*>(&Ks[sub * 16 + lq][ks * 32 + lg * 8]);
      sa[sub] = __builtin_amdgcn_mfma_f32_16x16x32_bf16(kf, qf[ks], sa[sub], 0, 0, 0);
    }
  const size_t KL = (size_t)(qt + 1) * 128;
  unsigned short* Prow = P + (size_t)b * P_PER_B +
                         (size_t)(qt * (qt + 1) / 2) * P_TILE + (size_t)qloc * KL +
                         kt * 128;
  float ps = 0.0f;
  const bool diag = (kt == qt);
#pragma unroll
  for (int sub = 0; sub < 8; sub++) {
    bf16x4v pv;
#pragma unroll
    for (int r = 0; r < 4; r++) {
      const int kvloc = sub * 16 + lg * 4 + r;
      float p;
      if (diag && kvloc > qloc) {
        p = 0.0f;
      } else {
        const float dn = (float)((kt - qt) * 128 + kvloc - qloc) + pbm;
        const float s = sa[sub][r] * SCALE + 1.0f / (1.0f + __expf(-dn));
        p = __expf(s);
      }
      ps += p;
      pv[r] = (__bf16)p;
    }
    *reinterpret_cast<bf16x4v*>(Prow + sub * 16 + lg * 4) = pv;
  }
  ps += __shfl_xor(ps, 16);
  ps += __shfl_xor(ps, 32);
  if (lane < 16) atomicAdd(&l[b * NSEQ + qt * 128 + w * 16 + lane], ps);
}

// ---------------- PV kernel: O[128, 128] = P[128, KL] @ vT^T, /l, -> concat ------
__global__ __launch_bounds__(256, 4) void pv_kernel(
    const unsigned short* __restrict__ P, const unsigned short* __restrict__ vT,
    const float* __restrict__ l, unsigned short* __restrict__ concat) {
  __shared__ unsigned short As[128][64];
  __shared__ unsigned short Bs[128][64];
  const int tid = threadIdx.x;
  const int bid = blockIdx.x;
  const int qt = 31 - (bid >> 5);  // heavy tiles dispatched first
  const int rest = bid & 31;
  const int b = rest >> 3;
  const int nt = rest & 7;
  const int KL = (qt + 1) * 128;
  const unsigned short* A =
      P + (size_t)b * P_PER_B + (size_t)(qt * (qt + 1) / 2) * P_TILE;
  const unsigned short* Bt = vT + (size_t)b * DM * NSEQ;
  const int n0 = nt * 128;
  const int lane = tid & 63;
  const int w = tid >> 6;
  const int lr = lane & 15;
  const int lg = lane >> 4;
  const int wr = (w >> 1) * 64;
  const int wc = (w & 1) * 64;

  f32x4 acc[4][4];
#pragma unroll
  for (int i = 0; i < 4; i++)
#pragma unroll
    for (int j = 0; j < 4; j++)
#pragma unroll
      for (int r = 0; r < 4; r++) acc[i][j][r] = 0.0f;

  for (int k0 = 0; k0 < KL; k0 += 64) {
#pragma unroll
    for (int j = 0; j < 4; j++) {
      const int boff = w * 4096 + j * 1024 + lane * 16;
      const int row = boff >> 7;
      const int col = (boff & 127) >> 1;
      gload_lds16(A + (size_t)row * KL + k0 + col,
                  &As[0][0] + (boff - lane * 16) / 2);
    }
#pragma unroll
    for (int j = 0; j < 4; j++) {
      const int boff = w * 4096 + j * 1024 + lane * 16;
      const int row = boff >> 7;
      const int col = (boff & 127) >> 1;
      gload_lds16(Bt + (size_t)(n0 + row) * NSEQ + k0 + col,
                  &Bs[0][0] + (boff - lane * 16) / 2);
    }
    __syncthreads();
#pragma unroll
    for (int kk = 0; kk < 64; kk += 32) {
      bf16x8 af[4], bfr[4];
#pragma unroll
      for (int i = 0; i < 4; i++)
        af[i] =
            *reinterpret_cast<const bf16x8*>(&As[wr + i * 16 + lr][kk + lg * 8]);
#pragma unroll
      for (int j = 0; j < 4; j++)
        bfr[j] =
            *reinterpret_cast<const bf16x8*>(&Bs[wc + j * 16 + lr][kk + lg * 8]);
#pragma unroll
      for (int i = 0; i < 4; i++)
#pragma unroll
        for (int j = 0; j < 4; j++)
          acc[i][j] = __builtin_amdgcn_mfma_f32_16x16x32_bf16(af[i], bfr[j],
                                                              acc[i][j], 0, 0, 0);
    }
    __syncthreads();
  }

  const float* lb = l + b * NSEQ + qt * 128;
#pragma unroll
  for (int i = 0; i < 4; i++) {
    f32x4 lv = *reinterpret_cast<const f32x4*>(&lb[wr + i * 16 + lg * 4]);
    f32x4 inv;
#pragma unroll
    for (int r = 0; r < 4; r++) inv[r] = 1.0f / lv[r];
#pragma unroll
    for (int j = 0; j < 4; j++)
#pragma unroll
      for (int r = 0; r < 4; r++) {
        const int grow = b * NSEQ + qt * 128 + wr + i * 16 + lg * 4 + r;
        const int col = 1024 + n0 + wc + j * 16 + lr;
        concat[(size_t)grow * 2048 + col] = f2bf(acc[i][j][r] * inv[r]);
      }
  }
}

extern "C" void kernel_launch(void* const* d_in, const int* in_sizes, int n_in,
                              void* d_out, int out_size, void* d_ws,
                              size_t ws_size, hipStream_t stream) {
  (void)in_sizes;
  (void)n_in;
  (void)out_size;
  const float* x = (const float*)d_in[0];
  const float* expand = (const float*)d_in[1];
  const float* project = (const float*)d_in[2];
  const float* pbm = (const float*)d_in[3];
  float* out = (float*)d_out;

  const size_t QK_BYTES = (size_t)16384 * 256 * 2;
  const size_t GH_BYTES = (size_t)16384 * 4096 * 2;
  const size_t CAT_BYTES = (size_t)16384 * 2048 * 2;
  const size_t NX_BYTES = (size_t)16384 * DM * 2;
  const size_t P_BYTES = (size_t)NBATCH * P_PER_B * 2;  // 69.2 MB
  if (ws_size < QK_BYTES + GH_BYTES + CAT_BYTES + NX_BYTES) return;

  char* ws = (char*)d_ws;
  unsigned short* qk = (unsigned short*)ws;
  unsigned short* gateH = (unsigned short*)(ws + QK_BYTES);
  unsigned short* concat = (unsigned short*)(ws + QK_BYTES + GH_BYTES);
  unsigned short* nx = (unsigned short*)(ws + QK_BYTES + GH_BYTES + CAT_BYTES);
  unsigned short* vT = nx;
  unsigned short* projectT = nx;
  unsigned short* expandT = concat;
  unsigned short* P = gateH;
  float* l = (float*)(ws + QK_BYTES + P_BYTES);

  // 0a. expandT[n][k] = bf16(expand[k][n])
  tconv_kernel<<<dim3(68, 16), 256, 0, stream>>>(expand, expandT, 1024, 4352);
  // 1. LayerNorm
  ln_kernel<<<16384, 256, 0, stream>>>(x, nx);
  // 2a. qk = nx @ expandT[0:256]^T   (M=16384, N=256, K=1024)
  gemm256_kernel<false><<<dim3(64), 512, 0, stream>>>(
      nx, DM, expandT, DM, (void*)qk, 256, DM, 1, nullptr);
  // 2b. gateH = nx @ expandT[256:4352]^T  (M=16384, N=4096, K=1024)
  gemm256_kernel<false><<<dim3(64 * 16), 512, 0, stream>>>(
      nx, DM, expandT + (size_t)256 * DM, DM, (void*)gateH, 4096, DM, 16, nullptr);
  // 3. local half of concat
  gate_local_kernel<<<8192, 256, 0, stream>>>(gateH, concat);
  // 4. v transposed (nx dead)
  gate_vt_kernel<<<dim3(64, 16, 4), 256, 0, stream>>>(gateH, vT);
  // 5. P = softmax numerator (gateH dead -> P aliases it); l zeroed first
  hipMemsetAsync(l, 0, (size_t)NBATCH * NSEQ * 4, stream);
  pk_kernel<<<dim3(NBATCH * 528), 512, 0, stream>>>(qk, pbm, P, l);
  // 6. attn = (P @ V) / l -> concat[:, 1024:2048]
  pv_kernel<<<dim3(1024), 256, 0, stream>>>(P, vT, l, concat);
  // 7. projectT (vT dead)
  tconv_kernel<<<dim3(16, 32), 256, 0, stream>>>(project, projectT, 2048, DM);
  // 8. out = x + concat @ projectT^T  (M=16384, N=1024, K=2048)
  gemm256_kernel<true><<<dim3(64 * 4), 512, 0, stream>>>(
      concat, 2048, projectT, 2048, (void*)out, DM, 2048, 4, x);
}

// Round 8
// 477.995 us; speedup vs baseline: 2.3714x; 1.0335x over previous
//
#include <hip/hip_runtime.h>
#include <type_traits>

typedef __bf16 bf16x8 __attribute__((ext_vector_type(8)));
typedef __bf16 bf16x4v __attribute__((ext_vector_type(4)));
typedef float f32x4 __attribute__((ext_vector_type(4)));
typedef unsigned short u16x8 __attribute__((ext_vector_type(8)));
typedef unsigned short u16x4 __attribute__((ext_vector_type(4)));

#define NSEQ 4096
#define DM 1024
#define NBATCH 4

__device__ __forceinline__ unsigned short f2bf(float f) {
  unsigned u = __float_as_uint(f);
  u += 0x7FFFu + ((u >> 16) & 1u);
  return (unsigned short)(u >> 16);
}
__device__ __forceinline__ float bf2f(unsigned short h) {
  return __uint_as_float(((unsigned)h) << 16);
}
__device__ __forceinline__ float gelu_exact(float x) {
  return 0.5f * x * (1.0f + erff(x * 0.7071067811865475f));
}

// async global->LDS, 16B per lane; lds dst is wave-uniform base + lane*16
__device__ __forceinline__ void gload_lds16(const unsigned short* src,
                                            unsigned short* dst) {
  __builtin_amdgcn_global_load_lds(
      (const __attribute__((address_space(1))) unsigned int*)src,
      (__attribute__((address_space(3))) unsigned int*)dst, 16, 0, 0);
}

#define BAR() asm volatile("s_barrier" ::: "memory")
#define VMCNT8() asm volatile("s_waitcnt vmcnt(8)" ::: "memory")

// ---------------- LayerNorm: x (f32) -> nx (bf16) ----------------
__global__ __launch_bounds__(256) void ln_kernel(const float* __restrict__ x,
                                                 unsigned short* __restrict__ nx) {
  const int row = blockIdx.x;
  const int tid = threadIdx.x;
  const float4 v = reinterpret_cast<const float4*>(x + (size_t)row * DM)[tid];
  float s = v.x + v.y + v.z + v.w;
  float q = v.x * v.x + v.y * v.y + v.z * v.z + v.w * v.w;
#pragma unroll
  for (int off = 32; off > 0; off >>= 1) {
    s += __shfl_down(s, off);
    q += __shfl_down(q, off);
  }
  __shared__ float ss[4], sq[4];
  if ((tid & 63) == 0) {
    ss[tid >> 6] = s;
    sq[tid >> 6] = q;
  }
  __syncthreads();
  const float ts = ss[0] + ss[1] + ss[2] + ss[3];
  const float tq = sq[0] + sq[1] + sq[2] + sq[3];
  const float mu = ts * (1.0f / DM);
  const float var = tq * (1.0f / DM) - mu * mu;
  const float rs = rsqrtf(var + 1e-5f);
  u16x4 o;
  o[0] = f2bf((v.x - mu) * rs);
  o[1] = f2bf((v.y - mu) * rs);
  o[2] = f2bf((v.z - mu) * rs);
  o[3] = f2bf((v.w - mu) * rs);
  *reinterpret_cast<u16x4*>(nx + (size_t)row * DM + tid * 4) = o;
}

// ---------------- transpose+convert: in f32 [K][N] -> out bf16 [N][K] -------------
__global__ __launch_bounds__(256) void tconv_kernel(const float* __restrict__ in,
                                                    unsigned short* __restrict__ out,
                                                    int K, int N) {
  __shared__ unsigned short tile[64][72];
  const int n0 = blockIdx.x * 64;
  const int k0 = blockIdx.y * 64;
  const int tid = threadIdx.x;
  const int lr = tid >> 4, lc = (tid & 15) * 4;
#pragma unroll
  for (int p = 0; p < 4; p++) {
    const int r = lr + p * 16;
    float4 v = *reinterpret_cast<const float4*>(in + (size_t)(k0 + r) * N + n0 + lc);
    tile[r][lc + 0] = f2bf(v.x);
    tile[r][lc + 1] = f2bf(v.y);
    tile[r][lc + 2] = f2bf(v.z);
    tile[r][lc + 3] = f2bf(v.w);
  }
  __syncthreads();
  const int nn = tid >> 2, kkg = (tid & 3) * 16;
  u16x8 o0, o1;
#pragma unroll
  for (int j = 0; j < 8; j++) {
    o0[j] = tile[kkg + j][nn];
    o1[j] = tile[kkg + 8 + j][nn];
  }
  unsigned short* dst = out + (size_t)(n0 + nn) * K + k0 + kkg;
  *reinterpret_cast<u16x8*>(dst) = o0;
  *reinterpret_cast<u16x8*>(dst + 8) = o1;
}

// ---------------- 256x256 8-phase GEMM: C[M,N] = A[M,K] @ Bt[N,K] (bf16) ----------
// 512 thr = 8 waves (2M x 4N), BK=64, LDS 128 KiB as [dbuf][khalf][256][32].
// T2 swizzle: logical (row, 16B-chunk c) stored at physical chunk c ^ ((row>>1)&3).
// Write side: global_load_lds dest LINEAR, SOURCE col pre-swizzled (involution).
// Read side: frag col = lg*8 XOR ((lq>>1)&3)<<3  -> 2 lanes/bank = conflict-free.
// Stage order: ph0->A-kh1(T+1), ph1->B-kh1(T+1), ph2->A-kh0(T+2), ph3->B-kh0(T+2).
// vmcnt(8) after ph1/ph3 stage issues (loads guarded are >=8 issues old).
template <bool FINAL>
__global__ __launch_bounds__(512, 2) void gemm256_kernel(
    const unsigned short* __restrict__ A, int lda,
    const unsigned short* __restrict__ Bt, int ldb, void* __restrict__ Cv,
    int ldc, int K, int ntn, const float* __restrict__ X) {
  __shared__ unsigned short Ah[2][2][8192];  // [dbuf][khalf][row*32+k]
  __shared__ unsigned short Bh[2][2][8192];
  const int tid = threadIdx.x;
  const int lane = tid & 63;
  const int w = tid >> 6;
  const int lq = lane & 15;
  const int lg = lane >> 4;
  const int wm = w >> 2;  // 0..1
  const int wn = w & 3;   // 0..3
  const int bid = blockIdx.x;
  const int m0 = (bid / ntn) * 256;
  const int n0 = (bid % ntn) * 256;
  const int nk = K >> 6;

  // staging geometry: chunk g = j*512 + w*64 + lane; row = g>>2, chunk = g&3.
  // source col pre-swizzled: kcS = ((g&3)*8) ^ (((row>>1)&3)<<3)
  const int g0 = w * 64 + lane;
  const int rowS = g0 >> 2;
  const int kcS = ((g0 & 3) * 8) ^ (((rowS >> 1) & 3) << 3);
  const unsigned short* Asrc = A + (size_t)(m0 + rowS) * lda + kcS;
  const unsigned short* Bsrc = Bt + (size_t)(n0 + rowS) * ldb + kcS;
  const size_t ldaj = (size_t)128 * lda;  // rows 128..255: same swizzle (bits 1-2)
  const size_t ldbj = (size_t)128 * ldb;
  const int dstW = w * 64 * 8;  // ushort offset of this wave's slice (j=0)

  auto stageA = [&](int db, int kh, int kt2) {
    if (kt2 < nk) {
      const unsigned short* s = Asrc + (size_t)kt2 * 64 + kh * 32;
      unsigned short* d = &Ah[db][kh][0] + dstW;
      gload_lds16(s, d);
      gload_lds16(s + ldaj, d + 4096);
    }
  };
  auto stageB = [&](int db, int kh, int kt2) {
    if (kt2 < nk) {
      const unsigned short* s = Bsrc + (size_t)kt2 * 64 + kh * 32;
      unsigned short* d = &Bh[db][kh][0] + dstW;
      gload_lds16(s, d);
      gload_lds16(s + ldbj, d + 4096);
    }
  };

  f32x4 acc[8][4];
#pragma unroll
  for (int i = 0; i < 8; i++)
#pragma unroll
    for (int j = 0; j < 4; j++)
#pragma unroll
      for (int r = 0; r < 4; r++) acc[i][j][r] = 0.0f;

  // prologue: A0,B0,A1,B1 of tile 0; A0,B0 of tile 1 (12 loads)
  stageA(0, 0, 0);
  stageB(0, 0, 0);
  stageA(0, 1, 0);
  stageB(0, 1, 0);
  stageA(1, 0, 1);
  stageB(1, 0, 1);
  VMCNT8();
  BAR();

  const int aBase = wm * 128;
  const int bBase = wn * 64;
  // read-side swizzled col (row bits 1-2 == lq bits 1-2 for all frag rows)
  const int cSwz = (lg * 8) ^ (((lq >> 1) & 3) << 3);

#pragma unroll 1
  for (int kt = 0; kt < nk; ++kt) {
    const int buf = kt & 1;
    bf16x8 af[4], bf0[4], bf1[4];

    // ---- phase 0: kh0, rows 0-63; stage A-kh1(kt+1)
#pragma unroll
    for (int i = 0; i < 4; i++)
      af[i] = *reinterpret_cast<const bf16x8*>(
          &Ah[buf][0][(aBase + i * 16 + lq) * 32 + cSwz]);
#pragma unroll
    for (int j = 0; j < 4; j++)
      bf0[j] = *reinterpret_cast<const bf16x8*>(
          &Bh[buf][0][(bBase + j * 16 + lq) * 32 + cSwz]);
    stageA(buf ^ 1, 1, kt + 1);
    BAR();
    __builtin_amdgcn_s_setprio(1);
#pragma unroll
    for (int i = 0; i < 4; i++)
#pragma unroll
      for (int j = 0; j < 4; j++)
        acc[i][j] =
            __builtin_amdgcn_mfma_f32_16x16x32_bf16(af[i], bf0[j], acc[i][j], 0, 0, 0);
    __builtin_amdgcn_s_setprio(0);
    BAR();

    // ---- phase 1: kh0, rows 64-127; stage B-kh1(kt+1); vmcnt(8)
#pragma unroll
    for (int i = 0; i < 4; i++)
      af[i] = *reinterpret_cast<const bf16x8*>(
          &Ah[buf][0][(aBase + 64 + i * 16 + lq) * 32 + cSwz]);
    stageB(buf ^ 1, 1, kt + 1);
    VMCNT8();
    BAR();
    __builtin_amdgcn_s_setprio(1);
#pragma unroll
    for (int i = 0; i < 4; i++)
#pragma unroll
      for (int j = 0; j < 4; j++)
        acc[4 + i][j] = __builtin_amdgcn_mfma_f32_16x16x32_bf16(af[i], bf0[j],
                                                                acc[4 + i][j], 0, 0, 0);
    __builtin_amdgcn_s_setprio(0);
    BAR();

    // ---- phase 2: kh1, rows 0-63; stage A-kh0(kt+2)
#pragma unroll
    for (int i = 0; i < 4; i++)
      af[i] = *reinterpret_cast<const bf16x8*>(
          &Ah[buf][1][(aBase + i * 16 + lq) * 32 + cSwz]);
#pragma unroll
    for (int j = 0; j < 4; j++)
      bf1[j] = *reinterpret_cast<const bf16x8*>(
          &Bh[buf][1][(bBase + j * 16 + lq) * 32 + cSwz]);
    stageA(buf, 0, kt + 2);
    BAR();
    __builtin_amdgcn_s_setprio(1);
#pragma unroll
    for (int i = 0; i < 4; i++)
#pragma unroll
      for (int j = 0; j < 4; j++)
        acc[i][j] =
            __builtin_amdgcn_mfma_f32_16x16x32_bf16(af[i], bf1[j], acc[i][j], 0, 0, 0);
    __builtin_amdgcn_s_setprio(0);
    BAR();

    // ---- phase 3: kh1, rows 64-127; stage B-kh0(kt+2); vmcnt(8)
#pragma unroll
    for (int i = 0; i < 4; i++)
      af[i] = *reinterpret_cast<const bf16x8*>(
          &Ah[buf][1][(aBase + 64 + i * 16 + lq) * 32 + cSwz]);
    stageB(buf, 0, kt + 2);
    VMCNT8();
    BAR();
    __builtin_amdgcn_s_setprio(1);
#pragma unroll
    for (int i = 0; i < 4; i++)
#pragma unroll
      for (int j = 0; j < 4; j++)
        acc[4 + i][j] = __builtin_amdgcn_mfma_f32_16x16x32_bf16(af[i], bf1[j],
                                                                acc[4 + i][j], 0, 0, 0);
    __builtin_amdgcn_s_setprio(0);
    BAR();
  }

  if (FINAL) {
    float* C = reinterpret_cast<float*>(Cv);
#pragma unroll
    for (int I = 0; I < 8; I++)
#pragma unroll
      for (int j = 0; j < 4; j++)
#pragma unroll
        for (int r = 0; r < 4; r++) {
          const int row = m0 + wm * 128 + I * 16 + lg * 4 + r;
          const int col = n0 + wn * 64 + j * 16 + lq;
          const size_t off = (size_t)row * ldc + col;
          C[off] = X[off] + acc[I][j][r];
        }
  } else {
    unsigned short* C = reinterpret_cast<unsigned short*>(Cv);
#pragma unroll
    for (int I = 0; I < 8; I++)
#pragma unroll
      for (int j = 0; j < 4; j++)
#pragma unroll
        for (int r = 0; r < 4; r++) {
          const int row = m0 + wm * 128 + I * 16 + lg * 4 + r;
          const int col = n0 + wn * 64 + j * 16 + lq;
          C[(size_t)row * ldc + col] = f2bf(acc[I][j][r]);
        }
  }
}

// ---------------- gate: local = lin * gelu(pg) -> concat[:, 0:1024] ----------------
__global__ __launch_bounds__(256) void gate_local_kernel(
    const unsigned short* __restrict__ gateH, unsigned short* __restrict__ concat) {
  const int idx = blockIdx.x * 256 + threadIdx.x;
  const int row = idx >> 7;
  const int cg = idx & 127;
  const unsigned short* hr = gateH + (size_t)row * 4096;
  u16x8 lin = *reinterpret_cast<const u16x8*>(hr + cg * 8);
  u16x8 pg = *reinterpret_cast<const u16x8*>(hr + 2048 + cg * 8);
  u16x8 o;
#pragma unroll
  for (int j = 0; j < 8; j++) {
    const float l = bf2f(lin[j]);
    const float g = gelu_exact(bf2f(pg[j]));
    o[j] = f2bf(l * g);
  }
  *reinterpret_cast<u16x8*>(concat + (size_t)row * 2048 + cg * 8) = o;
}

// ---------------- gate: v = lin * gelu(pg), stored transposed vT[b][d][n] -------------
__global__ __launch_bounds__(256) void gate_vt_kernel(
    const unsigned short* __restrict__ gateH, unsigned short* __restrict__ vT) {
  __shared__ unsigned short tbuf[64][72];
  const int n0 = blockIdx.x * 64;
  const int d0 = blockIdx.y * 64;
  const int b = blockIdx.z;
  const int tid = threadIdx.x;
#pragma unroll
  for (int p = 0; p < 2; p++) {
    const int r = p * 32 + (tid >> 3);
    const int cg = tid & 7;
    const unsigned short* hr = gateH + (size_t)(b * NSEQ + n0 + r) * 4096;
    u16x8 lin = *reinterpret_cast<const u16x8*>(hr + 1024 + d0 + cg * 8);
    u16x8 pg = *reinterpret_cast<const u16x8*>(hr + 3072 + d0 + cg * 8);
    u16x8 o;
#pragma unroll
    for (int j = 0; j < 8; j++) {
      const float l = bf2f(lin[j]);
      const float g = gelu_exact(bf2f(pg[j]));
      o[j] = f2bf(l * g);
    }
    *reinterpret_cast<u16x8*>(&tbuf[r][cg * 8]) = o;
  }
  __syncthreads();
#pragma unroll
  for (int p = 0; p < 2; p++) {
    const int d = p * 32 + (tid >> 3);
    const int ng = tid & 7;
    u16x8 o;
#pragma unroll
    for (int j = 0; j < 8; j++) o[j] = tbuf[ng * 8 + j][d];
    *reinterpret_cast<u16x8*>(vT + (size_t)(b * DM + d0 + d) * NSEQ + n0 +
                              ng * 8) = o;
  }
}

// ---------------- P kernel: one causal 128x128 tile per block --------------------
#define P_TILE 16384           // 128*128
#define P_PER_B 8650752        // 528 tiles * 16384
__global__ __launch_bounds__(512, 4) void pk_kernel(
    const unsigned short* __restrict__ qk, const float* __restrict__ pbm_ptr,
    unsigned short* __restrict__ P, float* __restrict__ l) {
  __shared__ unsigned short Ks[128][136];
  const int tid = threadIdx.x;
  const int lane = tid & 63;
  const int w = tid >> 6;
  const int lq = lane & 15;
  const int lg = lane >> 4;
  const int bid = blockIdx.x;
  const int b = bid / 528;
  const int t = bid - b * 528;
  int qt = (int)((sqrtf((float)(8 * t + 1)) - 1.0f) * 0.5f);
  while ((qt + 1) * (qt + 2) / 2 <= t) ++qt;
  while (qt * (qt + 1) / 2 > t) --qt;
  const int kt = t - qt * (qt + 1) / 2;
  const float pbm = *pbm_ptr;
  const float SCALE = 0.08838834764831845f;

  const unsigned short* qb = qk + (size_t)b * NSEQ * 256;

#pragma unroll
  for (int p = 0; p < 4; p++) {
    const int task = tid + p * 512;
    const int row = task >> 4;
    const int ch = task & 15;
    bf16x8 v = *reinterpret_cast<const bf16x8*>(
        qb + (size_t)(kt * 128 + row) * 256 + 128 + ch * 8);
    *reinterpret_cast<bf16x8*>(&Ks[row][ch * 8]) = v;
  }
  const int qloc = w * 16 + lq;
  bf16x8 qf[4];
#pragma unroll
  for (int ks = 0; ks < 4; ks++)
    qf[ks] = *reinterpret_cast<const bf16x8*>(
        qb + (size_t)(qt * 128 + qloc) * 256 + ks * 32 + lg * 8);
  __syncthreads();

  f32x4 sa[8];
#pragma unroll
  for (int sub = 0; sub < 8; sub++)
#pragma unroll
    for (int r = 0; r < 4; r++) sa[sub][r] = 0.0f;
#pragma unroll
  for (int ks = 0; ks < 4; ks++)
#pragma unroll
    for (int sub = 0; sub < 8; sub++) {
      bf16x8 kf =
          *reinterpret_cast<const bf16x8*>(&Ks[sub * 16 + lq][ks * 32 + lg * 8]);
      sa[sub] = __builtin_amdgcn_mfma_f32_16x16x32_bf16(kf, qf[ks], sa[sub], 0, 0, 0);
    }
  const size_t KL = (size_t)(qt + 1) * 128;
  unsigned short* Prow = P + (size_t)b * P_PER_B +
                         (size_t)(qt * (qt + 1) / 2) * P_TILE + (size_t)qloc * KL +
                         kt * 128;
  float ps = 0.0f;
  const bool diag = (kt == qt);
#pragma unroll
  for (int sub = 0; sub < 8; sub++) {
    bf16x4v pv;
#pragma unroll
    for (int r = 0; r < 4; r++) {
      const int kvloc = sub * 16 + lg * 4 + r;
      float p;
      if (diag && kvloc > qloc) {
        p = 0.0f;
      } else {
        const float dn = (float)((kt - qt) * 128 + kvloc - qloc) + pbm;
        const float s = sa[sub][r] * SCALE + 1.0f / (1.0f + __expf(-dn));
        p = __expf(s);
      }
      ps += p;
      pv[r] = (__bf16)p;
    }
    *reinterpret_cast<bf16x4v*>(Prow + sub * 16 + lg * 4) = pv;
  }
  ps += __shfl_xor(ps, 16);
  ps += __shfl_xor(ps, 32);
  if (lane < 16) atomicAdd(&l[b * NSEQ + qt * 128 + w * 16 + lane], ps);
}

// ---------------- PV kernel: O[128, 128] = P[128, KL] @ vT^T, /l, -> concat ------
// T2 swizzle on [128][64]-ushort tiles: chunk col ^= (row&7)  (16B chunks).
__global__ __launch_bounds__(256, 4) void pv_kernel(
    const unsigned short* __restrict__ P, const unsigned short* __restrict__ vT,
    const float* __restrict__ l, unsigned short* __restrict__ concat) {
  __shared__ unsigned short As[128][64];
  __shared__ unsigned short Bs[128][64];
  const int tid = threadIdx.x;
  const int bid = blockIdx.x;
  const int qt = 31 - (bid >> 5);  // heavy tiles dispatched first
  const int rest = bid & 31;
  const int b = rest >> 3;
  const int nt = rest & 7;
  const int KL = (qt + 1) * 128;
  const unsigned short* A =
      P + (size_t)b * P_PER_B + (size_t)(qt * (qt + 1) / 2) * P_TILE;
  const unsigned short* Bt = vT + (size_t)b * DM * NSEQ;
  const int n0 = nt * 128;
  const int lane = tid & 63;
  const int w = tid >> 6;
  const int lr = lane & 15;
  const int lg = lane >> 4;
  const int wr = (w >> 1) * 64;
  const int wc = (w & 1) * 64;
  const int rSwz = (lr & 7) << 3;  // read-side swizzle (row&7 == lr&7)

  f32x4 acc[4][4];
#pragma unroll
  for (int i = 0; i < 4; i++)
#pragma unroll
    for (int j = 0; j < 4; j++)
#pragma unroll
      for (int r = 0; r < 4; r++) acc[i][j][r] = 0.0f;

  for (int k0 = 0; k0 < KL; k0 += 64) {
#pragma unroll
    for (int j = 0; j < 4; j++) {
      const int boff = w * 4096 + j * 1024 + lane * 16;
      const int row = boff >> 7;
      const int col = (((boff & 127) >> 1)) ^ ((row & 7) << 3);  // src pre-swizzle
      gload_lds16(A + (size_t)row * KL + k0 + col,
                  &As[0][0] + (boff - lane * 16) / 2);
    }
#pragma unroll
    for (int j = 0; j < 4; j++) {
      const int boff = w * 4096 + j * 1024 + lane * 16;
      const int row = boff >> 7;
      const int col = (((boff & 127) >> 1)) ^ ((row & 7) << 3);
      gload_lds16(Bt + (size_t)(n0 + row) * NSEQ + k0 + col,
                  &Bs[0][0] + (boff - lane * 16) / 2);
    }
    __syncthreads();
#pragma unroll
    for (int kk = 0; kk < 64; kk += 32) {
      bf16x8 af[4], bfr[4];
#pragma unroll
      for (int i = 0; i < 4; i++)
        af[i] = *reinterpret_cast<const bf16x8*>(
            &As[wr + i * 16 + lr][(kk + lg * 8) ^ rSwz]);
#pragma unroll
      for (int j = 0; j < 4; j++)
        bfr[j] = *reinterpret_cast<const bf16x8*>(
            &Bs[wc + j * 16 + lr][(kk + lg * 8) ^ rSwz]);
#pragma unroll
      for (int i = 0; i < 4; i++)
#pragma unroll
        for (int j = 0; j < 4; j++)
          acc[i][j] = __builtin_amdgcn_mfma_f32_16x16x32_bf16(af[i], bfr[j],
                                                              acc[i][j], 0, 0, 0);
    }
    __syncthreads();
  }

  const float* lb = l + b * NSEQ + qt * 128;
#pragma unroll
  for (int i = 0; i < 4; i++) {
    f32x4 lv = *reinterpret_cast<const f32x4*>(&lb[wr + i * 16 + lg * 4]);
    f32x4 inv;
#pragma unroll
    for (int r = 0; r < 4; r++) inv[r] = 1.0f / lv[r];
#pragma unroll
    for (int j = 0; j < 4; j++)
#pragma unroll
      for (int r = 0; r < 4; r++) {
        const int grow = b * NSEQ + qt * 128 + wr + i * 16 + lg * 4 + r;
        const int col = 1024 + n0 + wc + j * 16 + lr;
        concat[(size_t)grow * 2048 + col] = f2bf(acc[i][j][r] * inv[r]);
      }
  }
}

extern "C" void kernel_launch(void* const* d_in, const int* in_sizes, int n_in,
                              void* d_out, int out_size, void* d_ws,
                              size_t ws_size, hipStream_t stream) {
  (void)in_sizes;
  (void)n_in;
  (void)out_size;
  const float* x = (const float*)d_in[0];
  const float* expand = (const float*)d_in[1];
  const float* project = (const float*)d_in[2];
  const float* pbm = (const float*)d_in[3];
  float* out = (float*)d_out;

  const size_t QK_BYTES = (size_t)16384 * 256 * 2;
  const size_t GH_BYTES = (size_t)16384 * 4096 * 2;
  const size_t CAT_BYTES = (size_t)16384 * 2048 * 2;
  const size_t NX_BYTES = (size_t)16384 * DM * 2;
  const size_t P_BYTES = (size_t)NBATCH * P_PER_B * 2;  // 69.2 MB
  if (ws_size < QK_BYTES + GH_BYTES + CAT_BYTES + NX_BYTES) return;

  char* ws = (char*)d_ws;
  unsigned short* qk = (unsigned short*)ws;
  unsigned short* gateH = (unsigned short*)(ws + QK_BYTES);
  unsigned short* concat = (unsigned short*)(ws + QK_BYTES + GH_BYTES);
  unsigned short* nx = (unsigned short*)(ws + QK_BYTES + GH_BYTES + CAT_BYTES);
  unsigned short* vT = nx;
  unsigned short* projectT = nx;
  unsigned short* expandT = concat;
  unsigned short* P = gateH;
  float* l = (float*)(ws + QK_BYTES + P_BYTES);

  // 0a. expandT[n][k] = bf16(expand[k][n])
  tconv_kernel<<<dim3(68, 16), 256, 0, stream>>>(expand, expandT, 1024, 4352);
  // 1. LayerNorm
  ln_kernel<<<16384, 256, 0, stream>>>(x, nx);
  // 2a. qk = nx @ expandT[0:256]^T   (M=16384, N=256, K=1024)
  gemm256_kernel<false><<<dim3(64), 512, 0, stream>>>(
      nx, DM, expandT, DM, (void*)qk, 256, DM, 1, nullptr);
  // 2b. gateH = nx @ expandT[256:4352]^T  (M=16384, N=4096, K=1024)
  gemm256_kernel<false><<<dim3(64 * 16), 512, 0, stream>>>(
      nx, DM, expandT + (size_t)256 * DM, DM, (void*)gateH, 4096, DM, 16, nullptr);
  // 3. local half of concat
  gate_local_kernel<<<8192, 256, 0, stream>>>(gateH, concat);
  // 4. v transposed (nx dead)
  gate_vt_kernel<<<dim3(64, 16, 4), 256, 0, stream>>>(gateH, vT);
  // 5. P = softmax numerator (gateH dead -> P aliases it); l zeroed first
  hipMemsetAsync(l, 0, (size_t)NBATCH * NSEQ * 4, stream);
  pk_kernel<<<dim3(NBATCH * 528), 512, 0, stream>>>(qk, pbm, P, l);
  // 6. attn = (P @ V) / l -> concat[:, 1024:2048]
  pv_kernel<<<dim3(1024), 256, 0, stream>>>(P, vT, l, concat);
  // 7. projectT (vT dead)
  tconv_kernel<<<dim3(16, 32), 256, 0, stream>>>(project, projectT, 2048, DM);
  // 8. out = x + concat @ projectT^T  (M=16384, N=1024, K=2048)
  gemm256_kernel<true><<<dim3(64 * 4), 512, 0, stream>>>(
      concat, 2048, projectT, 2048, (void*)out, DM, 2048, 4, x);
}